// Round 1
// baseline (1022.881 us; speedup 1.0000x reference)
//
#include <hip/hip_runtime.h>
#include <hip/hip_bf16.h>
#include <math.h>

static constexpr int kB  = 16;
static constexpr int kN  = 1024;   // image tokens
static constexpr int kT  = 512;    // text tokens
static constexpr int kC  = 768;    // channels (EMB == INCH)
static constexpr float kEps = 1e-5f;

// ---------------------------------------------------------------------------
// GEMM: C[M,N] = alpha * (A x B) (+ bias[n])
//   A_KM=false: A row-major [M,K];  A_KM=true: A row-major [K,M]
//   B_KN=false: B row-major [N,K] (C = A*B^T);  B_KN=true: B row-major [K,N]
// 128x128 tile, 256 threads, 8x8 per thread, k-major LDS (stride 132 -> b128
// reads, <=2-way bank aliasing which is free on CDNA4).
// ---------------------------------------------------------------------------
template<bool A_KM, bool B_KN, bool HAS_BIAS>
__global__ __launch_bounds__(256, 2)
void gemm128(const float* __restrict__ A, const float* __restrict__ Bm,
             float* __restrict__ C, const float* __restrict__ bias,
             int M, int N, int K, float alpha,
             long strideA, long strideB, long strideC)
{
    __shared__ float As[16][132];
    __shared__ float Bs[16][132];
    const int bz = blockIdx.z;
    A  += (long)bz * strideA;
    Bm += (long)bz * strideB;
    C  += (long)bz * strideC;
    const int m0 = blockIdx.y * 128;
    const int n0 = blockIdx.x * 128;
    const int t  = threadIdx.x;
    const int tx = t & 15;
    const int ty = t >> 4;

    float acc[8][8];
#pragma unroll
    for (int i = 0; i < 8; ++i)
#pragma unroll
        for (int j = 0; j < 8; ++j) acc[i][j] = 0.f;

    for (int k0 = 0; k0 < K; k0 += 16) {
        __syncthreads();
        // ---- stage A tile ----
        if (!A_KM) {
            const int r  = t >> 2;
            const int kc = (t & 3) << 2;
            float4 a0 = *(const float4*)(A + (long)(m0 + r)      * K + (k0 + kc));
            float4 a1 = *(const float4*)(A + (long)(m0 + r + 64) * K + (k0 + kc));
            As[kc+0][r] = a0.x; As[kc+1][r] = a0.y; As[kc+2][r] = a0.z; As[kc+3][r] = a0.w;
            As[kc+0][r+64] = a1.x; As[kc+1][r+64] = a1.y; As[kc+2][r+64] = a1.z; As[kc+3][r+64] = a1.w;
        } else {
            const int kb = t >> 4;
            const int c0 = (t & 15) << 3;
            float4 a0 = *(const float4*)(A + (long)(k0 + kb) * M + (m0 + c0));
            float4 a1 = *(const float4*)(A + (long)(k0 + kb) * M + (m0 + c0 + 4));
            *(float4*)&As[kb][c0]     = a0;
            *(float4*)&As[kb][c0 + 4] = a1;
        }
        // ---- stage B tile ----
        if (!B_KN) {
            const int r  = t >> 2;
            const int kc = (t & 3) << 2;
            float4 b0 = *(const float4*)(Bm + (long)(n0 + r)      * K + (k0 + kc));
            float4 b1 = *(const float4*)(Bm + (long)(n0 + r + 64) * K + (k0 + kc));
            Bs[kc+0][r] = b0.x; Bs[kc+1][r] = b0.y; Bs[kc+2][r] = b0.z; Bs[kc+3][r] = b0.w;
            Bs[kc+0][r+64] = b1.x; Bs[kc+1][r+64] = b1.y; Bs[kc+2][r+64] = b1.z; Bs[kc+3][r+64] = b1.w;
        } else {
            const int kb = t >> 4;
            const int c0 = (t & 15) << 3;
            float4 b0 = *(const float4*)(Bm + (long)(k0 + kb) * N + (n0 + c0));
            float4 b1 = *(const float4*)(Bm + (long)(k0 + kb) * N + (n0 + c0 + 4));
            *(float4*)&Bs[kb][c0]     = b0;
            *(float4*)&Bs[kb][c0 + 4] = b1;
        }
        __syncthreads();
#pragma unroll
        for (int kk = 0; kk < 16; ++kk) {
            float4 a0 = *(float4*)&As[kk][ty * 4];
            float4 a1 = *(float4*)&As[kk][64 + ty * 4];
            float4 b0 = *(float4*)&Bs[kk][tx * 4];
            float4 b1 = *(float4*)&Bs[kk][64 + tx * 4];
            float av[8] = {a0.x, a0.y, a0.z, a0.w, a1.x, a1.y, a1.z, a1.w};
            float bv[8] = {b0.x, b0.y, b0.z, b0.w, b1.x, b1.y, b1.z, b1.w};
#pragma unroll
            for (int i = 0; i < 8; ++i)
#pragma unroll
                for (int j = 0; j < 8; ++j)
                    acc[i][j] = fmaf(av[i], bv[j], acc[i][j]);
        }
    }

    // ---- epilogue ----
    float4 bb0 = {0, 0, 0, 0}, bb1 = {0, 0, 0, 0};
    if (HAS_BIAS) {
        bb0 = *(const float4*)(bias + n0 + tx * 4);
        bb1 = *(const float4*)(bias + n0 + 64 + tx * 4);
    }
#pragma unroll
    for (int ih = 0; ih < 2; ++ih)
#pragma unroll
        for (int i = 0; i < 4; ++i) {
            const int m = m0 + ih * 64 + ty * 4 + i;
            float* crow = C + (long)m * N;
            float4 v0, v1;
            v0.x = acc[ih*4+i][0] * alpha; v0.y = acc[ih*4+i][1] * alpha;
            v0.z = acc[ih*4+i][2] * alpha; v0.w = acc[ih*4+i][3] * alpha;
            v1.x = acc[ih*4+i][4] * alpha; v1.y = acc[ih*4+i][5] * alpha;
            v1.z = acc[ih*4+i][6] * alpha; v1.w = acc[ih*4+i][7] * alpha;
            if (HAS_BIAS) {
                v0.x += bb0.x; v0.y += bb0.y; v0.z += bb0.z; v0.w += bb0.w;
                v1.x += bb1.x; v1.y += bb1.y; v1.z += bb1.z; v1.w += bb1.w;
            }
            *(float4*)(crow + n0 + tx * 4)      = v0;
            *(float4*)(crow + n0 + 64 + tx * 4) = v1;
        }
}

// ---------------------------------------------------------------------------
// Per-channel sum / sumsq over rows of X [R, 768] (BN train-mode stats).
// 256 threads: thread owns columns {t, t+256, t+512}; atomics once per block.
// ---------------------------------------------------------------------------
__global__ void colstats(const float* __restrict__ X, float* __restrict__ sum,
                         float* __restrict__ sumsq, int rows_per_block)
{
    const int c  = threadIdx.x;
    const long r0 = (long)blockIdx.x * rows_per_block;
    float s0 = 0, s1 = 0, s2 = 0, q0 = 0, q1 = 0, q2 = 0;
    for (int r = 0; r < rows_per_block; ++r) {
        const float* row = X + (r0 + r) * kC;
        float x0 = row[c], x1 = row[c + 256], x2 = row[c + 512];
        s0 += x0; q0 += x0 * x0;
        s1 += x1; q1 += x1 * x1;
        s2 += x2; q2 += x2 * x2;
    }
    atomicAdd(&sum[c],         s0); atomicAdd(&sumsq[c],         q0);
    atomicAdd(&sum[c + 256],   s1); atomicAdd(&sumsq[c + 256],   q1);
    atomicAdd(&sum[c + 512],   s2); atomicAdd(&sumsq[c + 512],   q2);
}

// ---------------------------------------------------------------------------
// In-place BN + ReLU on X [R, 768]
// ---------------------------------------------------------------------------
__global__ void bn_relu(float* __restrict__ X, const float* __restrict__ sum,
                        const float* __restrict__ sumsq,
                        const float* __restrict__ g, const float* __restrict__ bta,
                        float invR, long total4)
{
    for (long i = blockIdx.x * (long)blockDim.x + threadIdx.x; i < total4;
         i += (long)gridDim.x * blockDim.x) {
        float4 x = ((const float4*)X)[i];
        const int c = (int)((i * 4) % kC);
        float4 y;
#pragma unroll
        for (int j = 0; j < 4; ++j) {
            float mu  = sum[c + j] * invR;
            float var = sumsq[c + j] * invR - mu * mu;
            float xs  = (&x.x)[j];
            float yy  = g[c + j] * (xs - mu) * rsqrtf(var + kEps) + bta[c + j];
            (&y.x)[j] = fmaxf(yy, 0.f);
        }
        ((float4*)X)[i] = y;
    }
}

// ---------------------------------------------------------------------------
// Final: out = relu(BN2(X)) + image
// ---------------------------------------------------------------------------
__global__ void bn_relu_add(const float* __restrict__ X, const float* __restrict__ img,
                            float* __restrict__ out,
                            const float* __restrict__ sum, const float* __restrict__ sumsq,
                            const float* __restrict__ g, const float* __restrict__ bta,
                            float invR, long total4)
{
    for (long i = blockIdx.x * (long)blockDim.x + threadIdx.x; i < total4;
         i += (long)gridDim.x * blockDim.x) {
        float4 x  = ((const float4*)X)[i];
        float4 im = ((const float4*)img)[i];
        const int c = (int)((i * 4) % kC);
        float4 y;
#pragma unroll
        for (int j = 0; j < 4; ++j) {
            float mu  = sum[c + j] * invR;
            float var = sumsq[c + j] * invR - mu * mu;
            float xs  = (&x.x)[j];
            float yy  = g[c + j] * (xs - mu) * rsqrtf(var + kEps) + bta[c + j];
            (&y.x)[j] = fmaxf(yy, 0.f) + (&im.x)[j];
        }
        ((float4*)out)[i] = y;
    }
}

// ---------------------------------------------------------------------------
// Per-row (b,t): softmax max + denom over 1024 contiguous values, and the
// K-th largest value (top-k threshold) via bitonic sort in LDS.
// One block (256 threads) per row; 8192 rows.
// ---------------------------------------------------------------------------
__global__ __launch_bounds__(256)
void topk_stats(const float* __restrict__ attnT, const float* __restrict__ kfrac,
                float* __restrict__ thr, float* __restrict__ mxv,
                float* __restrict__ invden)
{
    __shared__ float buf[1024];
    __shared__ float red[256];
    const int row = blockIdx.x;           // b*512 + t
    const int b   = row >> 9;
    const int t   = threadIdx.x;
    const float* x = attnT + (long)row * kN;

    float4 v = ((const float4*)x)[t];
    ((float4*)buf)[t] = v;

    // row max
    float m = fmaxf(fmaxf(v.x, v.y), fmaxf(v.z, v.w));
    red[t] = m; __syncthreads();
#pragma unroll
    for (int s = 128; s > 0; s >>= 1) {
        if (t < s) red[t] = fmaxf(red[t], red[t + s]);
        __syncthreads();
    }
    const float M = red[0];
    __syncthreads();

    // sum of exp
    float e = expf(v.x - M) + expf(v.y - M) + expf(v.z - M) + expf(v.w - M);
    red[t] = e; __syncthreads();
#pragma unroll
    for (int s = 128; s > 0; s >>= 1) {
        if (t < s) red[t] += red[t + s];
        __syncthreads();
    }
    if (t == 0) { mxv[row] = M; invden[row] = 1.f / red[0]; }

    // top-k threshold
    int K = (int)rintf((float)kN * kfrac[b]);
    K = K < 0 ? 0 : (K > kN ? kN : K);
    float th;
    if (K <= 0) {
        th = __builtin_inff();
    } else if (K >= kN) {
        th = -__builtin_inff();
    } else {
        // bitonic sort descending
        for (int k = 2; k <= kN; k <<= 1)
            for (int j = k >> 1; j > 0; j >>= 1) {
                __syncthreads();
                for (int u = t; u < kN; u += 256) {
                    int p = u ^ j;
                    if (p > u) {
                        float a = buf[u], c = buf[p];
                        bool desc = ((u & k) == 0);
                        if (desc ? (a < c) : (a > c)) { buf[u] = c; buf[p] = a; }
                    }
                }
            }
        __syncthreads();
        th = buf[K - 1];
    }
    if (t == 0) thr[row] = th;
}

// ---------------------------------------------------------------------------
// In-place: attnT -> masked softmax weights
// ---------------------------------------------------------------------------
__global__ void w_apply(float* __restrict__ A, const float* __restrict__ thr,
                        const float* __restrict__ mxv, const float* __restrict__ invden,
                        long total4)
{
    for (long i = blockIdx.x * (long)blockDim.x + threadIdx.x; i < total4;
         i += (long)gridDim.x * blockDim.x) {
        float4 x = ((const float4*)A)[i];
        const int row = (int)((i * 4) >> 10);   // kN = 1024 per row
        const float th = thr[row], M = mxv[row], d = invden[row];
        float4 y;
        y.x = (x.x >= th) ? expf(x.x - M) * d : 0.f;
        y.y = (x.y >= th) ? expf(x.y - M) * d : 0.f;
        y.z = (x.z >= th) ? expf(x.z - M) * d : 0.f;
        y.w = (x.w >= th) ? expf(x.w - M) * d : 0.f;
        ((float4*)A)[i] = y;
    }
}

// ---------------------------------------------------------------------------
extern "C" void kernel_launch(void* const* d_in, const int* in_sizes, int n_in,
                              void* d_out, int out_size, void* d_ws, size_t ws_size,
                              hipStream_t stream)
{
    const float* image = (const float*)d_in[0];   // [16,1024,768]
    const float* text  = (const float*)d_in[1];   // [16,512,768]
    const float* kfrac = (const float*)d_in[2];   // [16]
    const float* Wc    = (const float*)d_in[3];   // [768,768]
    const float* bc    = (const float*)d_in[4];
    const float* g1    = (const float*)d_in[5];
    const float* b1    = (const float*)d_in[6];
    const float* Wout  = (const float*)d_in[7];   // [768,768]
    const float* bout  = (const float*)d_in[8];
    const float* g2    = (const float*)d_in[9];
    const float* b2    = (const float*)d_in[10];
    float* out = (float*)d_out;

    // workspace layout (floats)
    float* temb  = (float*)d_ws;                    // 16*512*768  = 6291456
    float* v     = temb  + (long)kB * kT * kC;      // 6291456
    float* attnT = v     + (long)kB * kT * kC;      // 16*512*1024 = 8388608
    float* outp  = attnT + (long)kB * kT * kN;      // 16*1024*768 = 12582912
    float* stats = outp  + (long)kB * kN * kC;      // 4*768
    float* thr   = stats + 4 * kC;                  // 8192
    float* mxv   = thr   + kB * kT;
    float* invd  = mxv   + kB * kT;

    // zero BN accumulators (ws is poisoned before every call)
    hipMemsetAsync(stats, 0, 4 * kC * sizeof(float), stream);

    const float inv_sqrt_c = 1.0f / sqrtf((float)kC);

    // 1) Y1 = text @ Wc^T + bc            [8192, 768]
    gemm128<false, false, true><<<dim3(kC / 128, (kB * kT) / 128, 1), 256, 0, stream>>>(
        text, Wc, temb, bc, kB * kT, kC, kC, 1.0f, 0, 0, 0);

    // 2) BN1 stats + apply (+ReLU) in place -> temb
    colstats<<<dim3((kB * kT) / 64), 256, 0, stream>>>(temb, stats, stats + kC, 64);
    bn_relu<<<dim3(2048), 256, 0, stream>>>(temb, stats, stats + kC, g1, b1,
                                            1.0f / (kB * kT),
                                            (long)kB * kT * kC / 4);

    // 3) v = text @ Wout^T + bout         [8192, 768]
    gemm128<false, false, true><<<dim3(kC / 128, (kB * kT) / 128, 1), 256, 0, stream>>>(
        text, Wout, v, bout, kB * kT, kC, kC, 1.0f, 0, 0, 0);

    // 4) attnT[b] = temb[b] @ image[b]^T / sqrt(C)    [512, 1024] per batch
    gemm128<false, false, false><<<dim3(kN / 128, kT / 128, kB), 256, 0, stream>>>(
        temb, image, attnT, nullptr, kT, kN, kC, inv_sqrt_c,
        (long)kT * kC, (long)kN * kC, (long)kT * kN);

    // 5) per-row softmax stats + top-k threshold
    topk_stats<<<dim3(kB * kT), 256, 0, stream>>>(attnT, kfrac, thr, mxv, invd);

    // 6) attnT -> masked softmax weights (in place)
    w_apply<<<dim3(2048), 256, 0, stream>>>(attnT, thr, mxv, invd,
                                            (long)kB * kT * kN / 4);

    // 7) outp[b] = W^T[b] @ v[b]          [1024, 768] per batch (TN GEMM)
    gemm128<true, true, false><<<dim3(kC / 128, kN / 128, kB), 256, 0, stream>>>(
        attnT, v, outp, nullptr, kN, kC, kT, 1.0f,
        (long)kT * kN, (long)kT * kC, (long)kN * kC);

    // 8) BN2 stats + apply (+ReLU) + residual -> out
    colstats<<<dim3((kB * kN) / 64), 256, 0, stream>>>(outp, stats + 2 * kC,
                                                       stats + 3 * kC, 64);
    bn_relu_add<<<dim3(2048), 256, 0, stream>>>(outp, image, out,
                                                stats + 2 * kC, stats + 3 * kC,
                                                g2, b2, 1.0f / (kB * kN),
                                                (long)kB * kN * kC / 4);
}

// Round 2
// 805.433 us; speedup vs baseline: 1.2700x; 1.2700x over previous
//
#include <hip/hip_runtime.h>
#include <hip/hip_bf16.h>
#include <math.h>

static constexpr int kB  = 16;
static constexpr int kN  = 1024;   // image tokens
static constexpr int kT  = 512;    // text tokens
static constexpr int kC  = 768;    // channels (EMB == INCH)
static constexpr float kEps = 1e-5f;

// ---------------------------------------------------------------------------
// GEMM: C[M,N] = alpha * (A x B) (+ bias[n])
//   A_KM=false: A row-major [M,K];  A_KM=true: A row-major [K,M]
//   B_KN=false: B row-major [N,K] (C = A*B^T);  B_KN=true: B row-major [K,N]
// 128x128 tile, 256 threads, 8x8 per thread, k-major LDS (stride 132 -> b128
// reads, <=2-way bank aliasing which is free on CDNA4).
// ---------------------------------------------------------------------------
template<bool A_KM, bool B_KN, bool HAS_BIAS>
__global__ __launch_bounds__(256, 2)
void gemm128(const float* __restrict__ A, const float* __restrict__ Bm,
             float* __restrict__ C, const float* __restrict__ bias,
             int M, int N, int K, float alpha,
             long strideA, long strideB, long strideC)
{
    __shared__ float As[16][132];
    __shared__ float Bs[16][132];
    const int bz = blockIdx.z;
    A  += (long)bz * strideA;
    Bm += (long)bz * strideB;
    C  += (long)bz * strideC;
    const int m0 = blockIdx.y * 128;
    const int n0 = blockIdx.x * 128;
    const int t  = threadIdx.x;
    const int tx = t & 15;
    const int ty = t >> 4;

    float acc[8][8];
#pragma unroll
    for (int i = 0; i < 8; ++i)
#pragma unroll
        for (int j = 0; j < 8; ++j) acc[i][j] = 0.f;

    for (int k0 = 0; k0 < K; k0 += 16) {
        __syncthreads();
        // ---- stage A tile ----
        if (!A_KM) {
            const int r  = t >> 2;
            const int kc = (t & 3) << 2;
            float4 a0 = *(const float4*)(A + (long)(m0 + r)      * K + (k0 + kc));
            float4 a1 = *(const float4*)(A + (long)(m0 + r + 64) * K + (k0 + kc));
            As[kc+0][r] = a0.x; As[kc+1][r] = a0.y; As[kc+2][r] = a0.z; As[kc+3][r] = a0.w;
            As[kc+0][r+64] = a1.x; As[kc+1][r+64] = a1.y; As[kc+2][r+64] = a1.z; As[kc+3][r+64] = a1.w;
        } else {
            const int kb = t >> 4;
            const int c0 = (t & 15) << 3;
            float4 a0 = *(const float4*)(A + (long)(k0 + kb) * M + (m0 + c0));
            float4 a1 = *(const float4*)(A + (long)(k0 + kb) * M + (m0 + c0 + 4));
            *(float4*)&As[kb][c0]     = a0;
            *(float4*)&As[kb][c0 + 4] = a1;
        }
        // ---- stage B tile ----
        if (!B_KN) {
            const int r  = t >> 2;
            const int kc = (t & 3) << 2;
            float4 b0 = *(const float4*)(Bm + (long)(n0 + r)      * K + (k0 + kc));
            float4 b1 = *(const float4*)(Bm + (long)(n0 + r + 64) * K + (k0 + kc));
            Bs[kc+0][r] = b0.x; Bs[kc+1][r] = b0.y; Bs[kc+2][r] = b0.z; Bs[kc+3][r] = b0.w;
            Bs[kc+0][r+64] = b1.x; Bs[kc+1][r+64] = b1.y; Bs[kc+2][r+64] = b1.z; Bs[kc+3][r+64] = b1.w;
        } else {
            const int kb = t >> 4;
            const int c0 = (t & 15) << 3;
            float4 b0 = *(const float4*)(Bm + (long)(k0 + kb) * N + (n0 + c0));
            float4 b1 = *(const float4*)(Bm + (long)(k0 + kb) * N + (n0 + c0 + 4));
            *(float4*)&Bs[kb][c0]     = b0;
            *(float4*)&Bs[kb][c0 + 4] = b1;
        }
        __syncthreads();
#pragma unroll
        for (int kk = 0; kk < 16; ++kk) {
            float4 a0 = *(float4*)&As[kk][ty * 4];
            float4 a1 = *(float4*)&As[kk][64 + ty * 4];
            float4 b0 = *(float4*)&Bs[kk][tx * 4];
            float4 b1 = *(float4*)&Bs[kk][64 + tx * 4];
            float av[8] = {a0.x, a0.y, a0.z, a0.w, a1.x, a1.y, a1.z, a1.w};
            float bv[8] = {b0.x, b0.y, b0.z, b0.w, b1.x, b1.y, b1.z, b1.w};
#pragma unroll
            for (int i = 0; i < 8; ++i)
#pragma unroll
                for (int j = 0; j < 8; ++j)
                    acc[i][j] = fmaf(av[i], bv[j], acc[i][j]);
        }
    }

    // ---- epilogue ----
    float4 bb0 = {0, 0, 0, 0}, bb1 = {0, 0, 0, 0};
    if (HAS_BIAS) {
        bb0 = *(const float4*)(bias + n0 + tx * 4);
        bb1 = *(const float4*)(bias + n0 + 64 + tx * 4);
    }
#pragma unroll
    for (int ih = 0; ih < 2; ++ih)
#pragma unroll
        for (int i = 0; i < 4; ++i) {
            const int m = m0 + ih * 64 + ty * 4 + i;
            float* crow = C + (long)m * N;
            float4 v0, v1;
            v0.x = acc[ih*4+i][0] * alpha; v0.y = acc[ih*4+i][1] * alpha;
            v0.z = acc[ih*4+i][2] * alpha; v0.w = acc[ih*4+i][3] * alpha;
            v1.x = acc[ih*4+i][4] * alpha; v1.y = acc[ih*4+i][5] * alpha;
            v1.z = acc[ih*4+i][6] * alpha; v1.w = acc[ih*4+i][7] * alpha;
            if (HAS_BIAS) {
                v0.x += bb0.x; v0.y += bb0.y; v0.z += bb0.z; v0.w += bb0.w;
                v1.x += bb1.x; v1.y += bb1.y; v1.z += bb1.z; v1.w += bb1.w;
            }
            *(float4*)(crow + n0 + tx * 4)      = v0;
            *(float4*)(crow + n0 + 64 + tx * 4) = v1;
        }
}

// ---------------------------------------------------------------------------
// Per-channel sum / sumsq over rows of X [R, 768] (BN train-mode stats).
// ---------------------------------------------------------------------------
__global__ void colstats(const float* __restrict__ X, float* __restrict__ sum,
                         float* __restrict__ sumsq, int rows_per_block)
{
    const int c  = threadIdx.x;
    const long r0 = (long)blockIdx.x * rows_per_block;
    float s0 = 0, s1 = 0, s2 = 0, q0 = 0, q1 = 0, q2 = 0;
    for (int r = 0; r < rows_per_block; ++r) {
        const float* row = X + (r0 + r) * kC;
        float x0 = row[c], x1 = row[c + 256], x2 = row[c + 512];
        s0 += x0; q0 += x0 * x0;
        s1 += x1; q1 += x1 * x1;
        s2 += x2; q2 += x2 * x2;
    }
    atomicAdd(&sum[c],         s0); atomicAdd(&sumsq[c],         q0);
    atomicAdd(&sum[c + 256],   s1); atomicAdd(&sumsq[c + 256],   q1);
    atomicAdd(&sum[c + 512],   s2); atomicAdd(&sumsq[c + 512],   q2);
}

// ---------------------------------------------------------------------------
// In-place BN + ReLU on X [R, 768]
// ---------------------------------------------------------------------------
__global__ void bn_relu(float* __restrict__ X, const float* __restrict__ sum,
                        const float* __restrict__ sumsq,
                        const float* __restrict__ g, const float* __restrict__ bta,
                        float invR, long total4)
{
    for (long i = blockIdx.x * (long)blockDim.x + threadIdx.x; i < total4;
         i += (long)gridDim.x * blockDim.x) {
        float4 x = ((const float4*)X)[i];
        const int c = (int)((i * 4) % kC);
        float4 y;
#pragma unroll
        for (int j = 0; j < 4; ++j) {
            float mu  = sum[c + j] * invR;
            float var = sumsq[c + j] * invR - mu * mu;
            float xs  = (&x.x)[j];
            float yy  = g[c + j] * (xs - mu) * rsqrtf(var + kEps) + bta[c + j];
            (&y.x)[j] = fmaxf(yy, 0.f);
        }
        ((float4*)X)[i] = y;
    }
}

// ---------------------------------------------------------------------------
// Final: out = relu(BN2(X)) + image
// ---------------------------------------------------------------------------
__global__ void bn_relu_add(const float* __restrict__ X, const float* __restrict__ img,
                            float* __restrict__ out,
                            const float* __restrict__ sum, const float* __restrict__ sumsq,
                            const float* __restrict__ g, const float* __restrict__ bta,
                            float invR, long total4)
{
    for (long i = blockIdx.x * (long)blockDim.x + threadIdx.x; i < total4;
         i += (long)gridDim.x * blockDim.x) {
        float4 x  = ((const float4*)X)[i];
        float4 im = ((const float4*)img)[i];
        const int c = (int)((i * 4) % kC);
        float4 y;
#pragma unroll
        for (int j = 0; j < 4; ++j) {
            float mu  = sum[c + j] * invR;
            float var = sumsq[c + j] * invR - mu * mu;
            float xs  = (&x.x)[j];
            float yy  = g[c + j] * (xs - mu) * rsqrtf(var + kEps) + bta[c + j];
            (&y.x)[j] = fmaxf(yy, 0.f) + (&im.x)[j];
        }
        ((float4*)out)[i] = y;
    }
}

// ---------------------------------------------------------------------------
// Fused per-row (b,t) over 1024 contiguous values:
//   1) softmax max + denominator (full row, mask applied after softmax)
//   2) K-th-largest threshold via 4-pass radix-256 MSB select (no sort)
//   3) in-place write of masked softmax weights
// One block (256 threads) per row; each thread owns 4 values in registers.
// Replaces bitonic-sort topk_stats (224 us) + w_apply (~12 us).
// ---------------------------------------------------------------------------
__global__ __launch_bounds__(256)
void topk_fused(float* __restrict__ attnT, const float* __restrict__ kfrac)
{
    __shared__ __align__(16) unsigned hist[256];
    __shared__ float redf[4];
    __shared__ unsigned sh_sel;
    __shared__ int sh_K;

    const int row  = blockIdx.x;          // b*512 + t
    const int b    = row >> 9;
    const int t    = threadIdx.x;
    const int lane = t & 63;
    const int wv   = t >> 6;
    float* x = attnT + (long)row * kN;

    float4 v = ((const float4*)x)[t];

    // ---- row max (shuffle reduce, cross-wave via LDS) ----
    float m = fmaxf(fmaxf(v.x, v.y), fmaxf(v.z, v.w));
#pragma unroll
    for (int s = 32; s > 0; s >>= 1) m = fmaxf(m, __shfl_xor(m, s));
    if (lane == 0) redf[wv] = m;
    __syncthreads();
    const float M = fmaxf(fmaxf(redf[0], redf[1]), fmaxf(redf[2], redf[3]));
    __syncthreads();

    // ---- exp + denominator ----
    const float e0 = expf(v.x - M), e1 = expf(v.y - M);
    const float e2 = expf(v.z - M), e3 = expf(v.w - M);
    float e = (e0 + e1) + (e2 + e3);
#pragma unroll
    for (int s = 32; s > 0; s >>= 1) e += __shfl_xor(e, s);
    if (lane == 0) redf[wv] = e;
    __syncthreads();
    const float inv = 1.f / ((redf[0] + redf[1]) + (redf[2] + redf[3]));

    // ---- K-th largest via radix-256 select on order-preserving uint map ----
    int K = (int)rintf((float)kN * kfrac[b]);   // rintf = round-half-even, matches jnp.round
    float th;
    if (K <= 0) {
        th = __builtin_inff();
    } else if (K >= kN) {
        th = -__builtin_inff();
    } else {
        unsigned u[4];
#pragma unroll
        for (int j = 0; j < 4; ++j) {
            unsigned w = __float_as_uint((&v.x)[j]);
            u[j] = (w & 0x80000000u) ? ~w : (w | 0x80000000u);
        }
        unsigned prefix = 0;   // decided high bits of the K-th largest
        unsigned pm     = 0;   // mask of decided bits
        int Kr = K;
        for (int pos = 24; pos >= 0; pos -= 8) {
            hist[t] = 0;
            __syncthreads();
#pragma unroll
            for (int j = 0; j < 4; ++j)
                if ((u[j] & pm) == prefix)
                    atomicAdd(&hist[(u[j] >> pos) & 255u], 1u);
            __syncthreads();
            if (t < 64) {
                // lane t owns bins [4t .. 4t+3]; single b128 read
                uint4 h = *(const uint4*)&hist[4 * t];
                unsigned s3 = h.w;
                unsigned s2 = h.z + s3;
                unsigned s1 = h.y + s2;
                unsigned s0 = h.x + s1;          // lane-local suffix sums
                // inclusive suffix-scan of lane totals (no barriers, wave 0 only)
                unsigned acc = s0;
#pragma unroll
                for (int s = 1; s < 64; s <<= 1) {
                    unsigned o = __shfl_down(acc, s);
                    if (lane + s < 64) acc += o;
                }
                const unsigned hiLanes = acc - s0;   // sum over lanes > t
                const unsigned g0 = s0 + hiLanes;    // suffix incl. bin 4t
                const unsigned g1 = s1 + hiLanes;
                const unsigned g2 = s2 + hiLanes;
                const unsigned g3 = s3 + hiLanes;
                const unsigned kr = (unsigned)Kr;
                int dsel = -1; unsigned hex = 0;
                if      (g0 >= kr && g1 < kr)      { dsel = 4 * t + 0; hex = g1; }
                else if (g1 >= kr && g2 < kr)      { dsel = 4 * t + 1; hex = g2; }
                else if (g2 >= kr && g3 < kr)      { dsel = 4 * t + 2; hex = g3; }
                else if (g3 >= kr && hiLanes < kr) { dsel = 4 * t + 3; hex = hiLanes; }
                if (dsel >= 0) {
                    sh_sel = prefix | ((unsigned)dsel << pos);
                    sh_K   = (int)(kr - hex);
                }
            }
            __syncthreads();
            prefix = sh_sel;
            Kr     = sh_K;
            pm    |= (0xFFu << pos);
        }
        th = __uint_as_float((prefix & 0x80000000u) ? (prefix & 0x7FFFFFFFu)
                                                    : ~prefix);
    }

    // ---- in-place masked softmax weights ----
    float4 y;
    y.x = (v.x >= th) ? e0 * inv : 0.f;
    y.y = (v.y >= th) ? e1 * inv : 0.f;
    y.z = (v.z >= th) ? e2 * inv : 0.f;
    y.w = (v.w >= th) ? e3 * inv : 0.f;
    ((float4*)x)[t] = y;
}

// ---------------------------------------------------------------------------
extern "C" void kernel_launch(void* const* d_in, const int* in_sizes, int n_in,
                              void* d_out, int out_size, void* d_ws, size_t ws_size,
                              hipStream_t stream)
{
    const float* image = (const float*)d_in[0];   // [16,1024,768]
    const float* text  = (const float*)d_in[1];   // [16,512,768]
    const float* kfrac = (const float*)d_in[2];   // [16]
    const float* Wc    = (const float*)d_in[3];   // [768,768]
    const float* bc    = (const float*)d_in[4];
    const float* g1    = (const float*)d_in[5];
    const float* b1    = (const float*)d_in[6];
    const float* Wout  = (const float*)d_in[7];   // [768,768]
    const float* bout  = (const float*)d_in[8];
    const float* g2    = (const float*)d_in[9];
    const float* b2    = (const float*)d_in[10];
    float* out = (float*)d_out;

    // workspace layout (floats)
    float* temb  = (float*)d_ws;                    // 16*512*768
    float* v     = temb  + (long)kB * kT * kC;
    float* attnT = v     + (long)kB * kT * kC;      // 16*512*1024
    float* outp  = attnT + (long)kB * kT * kN;      // 16*1024*768
    float* stats = outp  + (long)kB * kN * kC;      // 4*768

    hipMemsetAsync(stats, 0, 4 * kC * sizeof(float), stream);

    const float inv_sqrt_c = 1.0f / sqrtf((float)kC);

    // 1) temb = text @ Wc^T + bc          [8192, 768]
    gemm128<false, false, true><<<dim3(kC / 128, (kB * kT) / 128, 1), 256, 0, stream>>>(
        text, Wc, temb, bc, kB * kT, kC, kC, 1.0f, 0, 0, 0);

    // 2) BN1 stats + apply (+ReLU) in place
    colstats<<<dim3((kB * kT) / 64), 256, 0, stream>>>(temb, stats, stats + kC, 64);
    bn_relu<<<dim3(2048), 256, 0, stream>>>(temb, stats, stats + kC, g1, b1,
                                            1.0f / (kB * kT),
                                            (long)kB * kT * kC / 4);

    // 3) v = text @ Wout^T + bout         [8192, 768]
    gemm128<false, false, true><<<dim3(kC / 128, (kB * kT) / 128, 1), 256, 0, stream>>>(
        text, Wout, v, bout, kB * kT, kC, kC, 1.0f, 0, 0, 0);

    // 4) attnT[b] = temb[b] @ image[b]^T / sqrt(C)    [512, 1024] per batch
    gemm128<false, false, false><<<dim3(kN / 128, kT / 128, kB), 256, 0, stream>>>(
        temb, image, attnT, nullptr, kT, kN, kC, inv_sqrt_c,
        (long)kT * kC, (long)kN * kC, (long)kT * kN);

    // 5+6) fused: softmax stats + radix-select top-k threshold + masked
    //      softmax weights written in place
    topk_fused<<<dim3(kB * kT), 256, 0, stream>>>(attnT, kfrac);

    // 7) outp[b] = attnT[b]^T @ v[b]      [1024, 768] per batch (TN GEMM)
    gemm128<true, true, false><<<dim3(kC / 128, kN / 128, kB), 256, 0, stream>>>(
        attnT, v, outp, nullptr, kN, kC, kT, 1.0f,
        (long)kT * kN, (long)kT * kC, (long)kN * kC);

    // 8) BN2 stats + apply (+ReLU) + residual -> out
    colstats<<<dim3((kB * kN) / 64), 256, 0, stream>>>(outp, stats + 2 * kC,
                                                       stats + 3 * kC, 64);
    bn_relu_add<<<dim3(2048), 256, 0, stream>>>(outp, image, out,
                                                stats + 2 * kC, stats + 3 * kC,
                                                g2, b2, 1.0f / (kB * kN),
                                                (long)kB * kN * kC / 4);
}

// Round 3
// 529.549 us; speedup vs baseline: 1.9316x; 1.5210x over previous
//
#include <hip/hip_runtime.h>
#include <hip/hip_bf16.h>
#include <math.h>

typedef __attribute__((ext_vector_type(8))) short short8;
typedef __attribute__((ext_vector_type(4))) float f32x4;

static constexpr int kB  = 16;
static constexpr int kN  = 1024;   // image tokens
static constexpr int kT  = 512;    // text tokens
static constexpr int kC  = 768;    // channels
static constexpr float kEps = 1e-5f;

__device__ inline unsigned short f2bf(float x) {        // RNE fp32 -> bf16
    unsigned u = __float_as_uint(x);
    u += 0x7FFFu + ((u >> 16) & 1u);
    return (unsigned short)(u >> 16);
}
__device__ inline float bf2f(unsigned short h) {
    return __uint_as_float(((unsigned)h) << 16);
}

// ---------------------------------------------------------------------------
// Split-bf16 MFMA GEMM:  C[M,N] = alpha * sum_seg A_seg x B_seg^T (+ bias[n])
// A: [M, 2K] bf16 rows = [hi | lo]; B: [N, 2K] bf16 rows = [hi | lo].
// 3 segments: (Ahi,Bhi), (Alo,Bhi), (Ahi,Blo)  ==  a*b to ~2^-17 rel.
// 128x128 tile, 4 waves (2x2), 16x16x32 MFMA, BK=32, single-buffer LDS,
// global_load_lds w=16 with XOR-swizzled source (rule #21: linear LDS dest,
// pre-swizzled global src, swizzled ds_read -> uniform bank coverage).
// ---------------------------------------------------------------------------
template<bool HAS_BIAS>
__global__ __launch_bounds__(256)
void gemm_sb(const unsigned short* __restrict__ A, const unsigned short* __restrict__ B,
             float* __restrict__ C, const float* __restrict__ bias,
             int N, int Kseg, float alpha, long sA, long sB, long sC)
{
    __shared__ unsigned short As[128 * 32];
    __shared__ unsigned short Bs[128 * 32];
    const int bz = blockIdx.z;
    A += bz * sA;  B += bz * sB;  C += bz * sC;
    const int m0 = blockIdx.y * 128, n0 = blockIdx.x * 128;
    const int tid = threadIdx.x, lane = tid & 63, wid = tid >> 6;
    const int wm = wid & 1, wn = wid >> 1;
    const long ld = 2 * (long)Kseg;

    f32x4 acc[4][4] = {};

    // staging constants: lane covers (row = base + lane/4, slot = lane&3);
    // fetch global slot s ^ f(row) so swizzled reads see linear k.
    const int srow  = lane >> 2;
    const int sslot = (lane & 3) ^ (srow & 3) ^ ((srow >> 2) & 3);
    // fragment-read swizzle (row low bits = lane&15):
    const int frow  = lane & 15;
    const int fslot = (lane >> 4) ^ (frow & 3) ^ ((frow >> 2) & 3);

    for (int seg = 0; seg < 3; ++seg) {
        const unsigned short* Ag = A + ((seg == 1) ? Kseg : 0);
        const unsigned short* Bg = B + ((seg == 2) ? Kseg : 0);
        for (int k0 = 0; k0 < Kseg; k0 += 32) {
            __syncthreads();
            {   // each wave stages 32 rows of A and 32 rows of B (2 x 1KB each)
                const int r0 = wid * 32;
                const unsigned short* ga = Ag + (long)(m0 + r0 + srow) * ld + k0 + sslot * 8;
                __builtin_amdgcn_global_load_lds(
                    (const __attribute__((address_space(1))) void*)ga,
                    (__attribute__((address_space(3))) void*)(As + r0 * 32), 16, 0, 0);
                __builtin_amdgcn_global_load_lds(
                    (const __attribute__((address_space(1))) void*)(ga + 16 * ld),
                    (__attribute__((address_space(3))) void*)(As + (r0 + 16) * 32), 16, 0, 0);
                const unsigned short* gb = Bg + (long)(n0 + r0 + srow) * ld + k0 + sslot * 8;
                __builtin_amdgcn_global_load_lds(
                    (const __attribute__((address_space(1))) void*)gb,
                    (__attribute__((address_space(3))) void*)(Bs + r0 * 32), 16, 0, 0);
                __builtin_amdgcn_global_load_lds(
                    (const __attribute__((address_space(1))) void*)(gb + 16 * ld),
                    (__attribute__((address_space(3))) void*)(Bs + (r0 + 16) * 32), 16, 0, 0);
            }
            __syncthreads();   // drains vmcnt (global_load_lds) + lgkm

            short8 af[4], bfr[4];
#pragma unroll
            for (int f = 0; f < 4; ++f) {
                af[f]  = *(const short8*)(As + (wm * 64 + f * 16 + frow) * 32 + fslot * 8);
                bfr[f] = *(const short8*)(Bs + (wn * 64 + f * 16 + frow) * 32 + fslot * 8);
            }
#pragma unroll
            for (int i = 0; i < 4; ++i)
#pragma unroll
                for (int j = 0; j < 4; ++j)
                    acc[i][j] = __builtin_amdgcn_mfma_f32_16x16x32_bf16(
                        af[i], bfr[j], acc[i][j], 0, 0, 0);
        }
    }

    // epilogue: C/D layout col=lane&15, row=(lane>>4)*4+reg
    const int cn = lane & 15, rq = lane >> 4;
#pragma unroll
    for (int j = 0; j < 4; ++j) {
        const int n = n0 + wn * 64 + j * 16 + cn;
        const float bv = HAS_BIAS ? bias[n] : 0.f;
#pragma unroll
        for (int i = 0; i < 4; ++i) {
            const int mr = m0 + wm * 64 + i * 16 + rq * 4;
#pragma unroll
            for (int r = 0; r < 4; ++r)
                C[(long)(mr + r) * N + n] = acc[i][j][r] * alpha + bv;
        }
    }
}

// ---------------------------------------------------------------------------
// Row-major split: in [R,K] fp32 -> out [R,2K] bf16 rows = [hi | lo]
// ---------------------------------------------------------------------------
__global__ void split2(const float* __restrict__ in, unsigned short* __restrict__ out,
                       int K, long total4)
{
    for (long i = blockIdx.x * (long)blockDim.x + threadIdx.x; i < total4;
         i += (long)gridDim.x * blockDim.x) {
        const long e = i * 4;
        const long row = e / K;
        const int  col = (int)(e - row * K);
        float4 x = *(const float4*)(in + e);
        ushort4 h, l;
        h.x = f2bf(x.x); l.x = f2bf(x.x - bf2f(h.x));
        h.y = f2bf(x.y); l.y = f2bf(x.y - bf2f(h.y));
        h.z = f2bf(x.z); l.z = f2bf(x.z - bf2f(h.z));
        h.w = f2bf(x.w); l.w = f2bf(x.w - bf2f(h.w));
        unsigned short* o = out + row * (long)(2 * K);
        *(ushort4*)(o + col)     = h;
        *(ushort4*)(o + K + col) = l;
    }
}

// ---------------------------------------------------------------------------
// Transpose + split (per batch): in [R,Cc] fp32 -> out [Cc, 2R] bf16
// ---------------------------------------------------------------------------
__global__ void split2_T(const float* __restrict__ in, unsigned short* __restrict__ out,
                         int R, int Cc, long sIn, long sOut)
{
    __shared__ float tile[32][33];
    const float* ib = in + (long)blockIdx.z * sIn;
    unsigned short* ob = out + (long)blockIdx.z * sOut;
    const int c0 = blockIdx.x * 32, r0 = blockIdx.y * 32;
    const int tx = threadIdx.x, ty = threadIdx.y;      // (32, 8)
#pragma unroll
    for (int it = 0; it < 4; ++it)
        tile[ty + 8 * it][tx] = ib[(long)(r0 + ty + 8 * it) * Cc + c0 + tx];
    __syncthreads();
#pragma unroll
    for (int it = 0; it < 4; ++it) {
        const int cc = ty + 8 * it;
        const float xv = tile[tx][cc];
        const unsigned short h = f2bf(xv);
        const unsigned short l = f2bf(xv - bf2f(h));
        unsigned short* o = ob + (long)(c0 + cc) * (2 * R) + r0 + tx;
        o[0] = h;  o[R] = l;
    }
}

// ---------------------------------------------------------------------------
// Per-channel sum / sumsq over rows of X [R, 768] (BN train-mode stats).
// ---------------------------------------------------------------------------
__global__ void colstats(const float* __restrict__ X, float* __restrict__ sum,
                         float* __restrict__ sumsq, int rows_per_block)
{
    const int c  = threadIdx.x;
    const long r0 = (long)blockIdx.x * rows_per_block;
    float s0 = 0, s1 = 0, s2 = 0, q0 = 0, q1 = 0, q2 = 0;
    for (int r = 0; r < rows_per_block; ++r) {
        const float* row = X + (r0 + r) * kC;
        float x0 = row[c], x1 = row[c + 256], x2 = row[c + 512];
        s0 += x0; q0 += x0 * x0;
        s1 += x1; q1 += x1 * x1;
        s2 += x2; q2 += x2 * x2;
    }
    atomicAdd(&sum[c],       s0); atomicAdd(&sumsq[c],       q0);
    atomicAdd(&sum[c + 256], s1); atomicAdd(&sumsq[c + 256], q1);
    atomicAdd(&sum[c + 512], s2); atomicAdd(&sumsq[c + 512], q2);
}

// ---------------------------------------------------------------------------
// BN1 + ReLU + split: temb fp32 [8192,768] -> temb2 bf16 [8192,1536]
// ---------------------------------------------------------------------------
__global__ void bn_relu_split2(const float* __restrict__ X, unsigned short* __restrict__ out,
                               const float* __restrict__ sum, const float* __restrict__ sumsq,
                               const float* __restrict__ g, const float* __restrict__ bta,
                               float invR, long total4)
{
    for (long i = blockIdx.x * (long)blockDim.x + threadIdx.x; i < total4;
         i += (long)gridDim.x * blockDim.x) {
        const long e = i * 4;
        const long row = e / kC;
        const int  c  = (int)(e - row * kC);
        float4 x = *(const float4*)(X + e);
        ushort4 h, l;
#pragma unroll
        for (int j = 0; j < 4; ++j) {
            const float mu  = sum[c + j] * invR;
            const float var = sumsq[c + j] * invR - mu * mu;
            float y = g[c + j] * ((&x.x)[j] - mu) * rsqrtf(var + kEps) + bta[c + j];
            y = fmaxf(y, 0.f);
            (&h.x)[j] = f2bf(y);
            (&l.x)[j] = f2bf(y - bf2f((&h.x)[j]));
        }
        unsigned short* o = out + row * (long)(2 * kC);
        *(ushort4*)(o + c)      = h;
        *(ushort4*)(o + kC + c) = l;
    }
}

// ---------------------------------------------------------------------------
// Final: out = relu(BN2(X)) + image
// ---------------------------------------------------------------------------
__global__ void bn_relu_add(const float* __restrict__ X, const float* __restrict__ img,
                            float* __restrict__ out,
                            const float* __restrict__ sum, const float* __restrict__ sumsq,
                            const float* __restrict__ g, const float* __restrict__ bta,
                            float invR, long total4)
{
    for (long i = blockIdx.x * (long)blockDim.x + threadIdx.x; i < total4;
         i += (long)gridDim.x * blockDim.x) {
        float4 x  = ((const float4*)X)[i];
        float4 im = ((const float4*)img)[i];
        const int c = (int)((i * 4) % kC);
        float4 y;
#pragma unroll
        for (int j = 0; j < 4; ++j) {
            const float mu  = sum[c + j] * invR;
            const float var = sumsq[c + j] * invR - mu * mu;
            const float yy  = g[c + j] * ((&x.x)[j] - mu) * rsqrtf(var + kEps) + bta[c + j];
            (&y.x)[j] = fmaxf(yy, 0.f) + (&im.x)[j];
        }
        ((float4*)out)[i] = y;
    }
}

// ---------------------------------------------------------------------------
// Fused per-row softmax stats + radix-256 top-k threshold + in-place masked
// softmax weights (unchanged from round 1 — was the fix that worked).
// ---------------------------------------------------------------------------
__global__ __launch_bounds__(256)
void topk_fused(float* __restrict__ attnT, const float* __restrict__ kfrac)
{
    __shared__ __align__(16) unsigned hist[256];
    __shared__ float redf[4];
    __shared__ unsigned sh_sel;
    __shared__ int sh_K;

    const int row  = blockIdx.x;
    const int b    = row >> 9;
    const int t    = threadIdx.x;
    const int lane = t & 63;
    const int wv   = t >> 6;
    float* x = attnT + (long)row * kN;

    float4 v = ((const float4*)x)[t];

    float m = fmaxf(fmaxf(v.x, v.y), fmaxf(v.z, v.w));
#pragma unroll
    for (int s = 32; s > 0; s >>= 1) m = fmaxf(m, __shfl_xor(m, s));
    if (lane == 0) redf[wv] = m;
    __syncthreads();
    const float M = fmaxf(fmaxf(redf[0], redf[1]), fmaxf(redf[2], redf[3]));
    __syncthreads();

    const float e0 = expf(v.x - M), e1 = expf(v.y - M);
    const float e2 = expf(v.z - M), e3 = expf(v.w - M);
    float e = (e0 + e1) + (e2 + e3);
#pragma unroll
    for (int s = 32; s > 0; s >>= 1) e += __shfl_xor(e, s);
    if (lane == 0) redf[wv] = e;
    __syncthreads();
    const float inv = 1.f / ((redf[0] + redf[1]) + (redf[2] + redf[3]));

    int K = (int)rintf((float)kN * kfrac[b]);
    float th;
    if (K <= 0) {
        th = __builtin_inff();
    } else if (K >= kN) {
        th = -__builtin_inff();
    } else {
        unsigned u[4];
#pragma unroll
        for (int j = 0; j < 4; ++j) {
            unsigned w = __float_as_uint((&v.x)[j]);
            u[j] = (w & 0x80000000u) ? ~w : (w | 0x80000000u);
        }
        unsigned prefix = 0, pm = 0;
        int Kr = K;
        for (int pos = 24; pos >= 0; pos -= 8) {
            hist[t] = 0;
            __syncthreads();
#pragma unroll
            for (int j = 0; j < 4; ++j)
                if ((u[j] & pm) == prefix)
                    atomicAdd(&hist[(u[j] >> pos) & 255u], 1u);
            __syncthreads();
            if (t < 64) {
                uint4 h = *(const uint4*)&hist[4 * t];
                unsigned s3 = h.w;
                unsigned s2 = h.z + s3;
                unsigned s1 = h.y + s2;
                unsigned s0 = h.x + s1;
                unsigned acc = s0;
#pragma unroll
                for (int s = 1; s < 64; s <<= 1) {
                    unsigned o = __shfl_down(acc, s);
                    if (lane + s < 64) acc += o;
                }
                const unsigned hiLanes = acc - s0;
                const unsigned g0 = s0 + hiLanes, g1 = s1 + hiLanes;
                const unsigned g2 = s2 + hiLanes, g3 = s3 + hiLanes;
                const unsigned kr = (unsigned)Kr;
                int dsel = -1; unsigned hex = 0;
                if      (g0 >= kr && g1 < kr)      { dsel = 4 * t + 0; hex = g1; }
                else if (g1 >= kr && g2 < kr)      { dsel = 4 * t + 1; hex = g2; }
                else if (g2 >= kr && g3 < kr)      { dsel = 4 * t + 2; hex = g3; }
                else if (g3 >= kr && hiLanes < kr) { dsel = 4 * t + 3; hex = hiLanes; }
                if (dsel >= 0) {
                    sh_sel = prefix | ((unsigned)dsel << pos);
                    sh_K   = (int)(kr - hex);
                }
            }
            __syncthreads();
            prefix = sh_sel;
            Kr     = sh_K;
            pm    |= (0xFFu << pos);
        }
        th = __uint_as_float((prefix & 0x80000000u) ? (prefix & 0x7FFFFFFFu) : ~prefix);
    }

    float4 y;
    y.x = (v.x >= th) ? e0 * inv : 0.f;
    y.y = (v.y >= th) ? e1 * inv : 0.f;
    y.z = (v.z >= th) ? e2 * inv : 0.f;
    y.w = (v.w >= th) ? e3 * inv : 0.f;
    ((float4*)x)[t] = y;
}

// ---------------------------------------------------------------------------
extern "C" void kernel_launch(void* const* d_in, const int* in_sizes, int n_in,
                              void* d_out, int out_size, void* d_ws, size_t ws_size,
                              hipStream_t stream)
{
    const float* image = (const float*)d_in[0];
    const float* text  = (const float*)d_in[1];
    const float* kfrac = (const float*)d_in[2];
    const float* Wc    = (const float*)d_in[3];
    const float* bc    = (const float*)d_in[4];
    const float* g1    = (const float*)d_in[5];
    const float* b1    = (const float*)d_in[6];
    const float* Wout  = (const float*)d_in[7];
    const float* bout  = (const float*)d_in[8];
    const float* g2    = (const float*)d_in[9];
    const float* b2    = (const float*)d_in[10];
    float* out = (float*)d_out;

    // ---- workspace arena (byte offsets, aliasing per liveness) ----
    char* ws = (char*)d_ws;
    unsigned short* Wc2    = (unsigned short*)(ws + 0);          //  2.36 MB
    unsigned short* Wout2  = (unsigned short*)(ws + 2359296);    //  2.36 MB
    float*          stats  = (float*)(ws + 4718592);             //  12 KB
    float*          v      = (float*)(ws + 4730880);             // 25.2 MB
    float*          attnT  = (float*)(ws + 29896704);            // 33.6 MB
    float*          temb   = (float*)(ws + 29896704);            // alias attnT (dead before)
    unsigned short* temb2  = (unsigned short*)(ws + 63451136);   // 25.2 MB
    unsigned short* image2 = (unsigned short*)(ws + 88616960);   // 50.3 MB
    unsigned short* text2  = (unsigned short*)(ws + 138948608);  // 25.2 MB -> end 164.1 MB
    unsigned short* attn2T = (unsigned short*)(ws + 63451136);   // alias temb2 (dead)
    unsigned short* v2T    = (unsigned short*)(ws + 97005568);   // alias image2 (dead)
    float*          outp   = (float*)(ws + 122171392);           // 50.3 MB -> end 172.5 MB

    hipMemsetAsync(stats, 0, 4 * kC * sizeof(float), stream);

    const float inv_sqrt_c = 1.0f / sqrtf((float)kC);

    // splits of raw inputs
    split2<<<dim3(1024), 256, 0, stream>>>(text,  text2,  kC, (long)kB * kT * kC / 4);
    split2<<<dim3(576),  256, 0, stream>>>(Wc,    Wc2,    kC, (long)kC * kC / 4);
    split2<<<dim3(576),  256, 0, stream>>>(Wout,  Wout2,  kC, (long)kC * kC / 4);
    split2<<<dim3(2048), 256, 0, stream>>>(image, image2, kC, (long)kB * kN * kC / 4);

    // 1) temb = text @ Wc^T + bc
    gemm_sb<true><<<dim3(kC / 128, (kB * kT) / 128, 1), 256, 0, stream>>>(
        text2, Wc2, temb, bc, kC, kC, 1.0f, 0, 0, 0);

    // 2) BN1 stats + apply + ReLU + split -> temb2
    colstats<<<dim3((kB * kT) / 64), 256, 0, stream>>>(temb, stats, stats + kC, 64);
    bn_relu_split2<<<dim3(1024), 256, 0, stream>>>(temb, temb2, stats, stats + kC,
                                                   g1, b1, 1.0f / (kB * kT),
                                                   (long)kB * kT * kC / 4);

    // 3) v = text @ Wout^T + bout
    gemm_sb<true><<<dim3(kC / 128, (kB * kT) / 128, 1), 256, 0, stream>>>(
        text2, Wout2, v, bout, kC, kC, 1.0f, 0, 0, 0);

    // 4) attnT[b] = temb[b] @ image[b]^T / sqrt(C)
    gemm_sb<false><<<dim3(kN / 128, kT / 128, kB), 256, 0, stream>>>(
        temb2, image2, attnT, nullptr, kN, kC, inv_sqrt_c,
        (long)kT * 2 * kC, (long)kN * 2 * kC, (long)kT * kN);

    // 5) fused softmax stats + top-k threshold + masked weights (in place)
    topk_fused<<<dim3(kB * kT), 256, 0, stream>>>(attnT, kfrac);

    // 6) transpose+split masked weights and v for the TN product
    split2_T<<<dim3(kN / 32, kT / 32, kB), dim3(32, 8), 0, stream>>>(
        attnT, attn2T, kT, kN, (long)kT * kN, (long)kN * 2 * kT);
    split2_T<<<dim3(kC / 32, kT / 32, kB), dim3(32, 8), 0, stream>>>(
        v, v2T, kT, kC, (long)kT * kC, (long)kC * 2 * kT);

    // 7) outp[b] = W[b] @ v[b]   (M=1024, N=768, Kseg=512)
    gemm_sb<false><<<dim3(kC / 128, kN / 128, kB), 256, 0, stream>>>(
        attn2T, v2T, outp, nullptr, kC, kT, 1.0f,
        (long)kN * 2 * kT, (long)kC * 2 * kT, (long)kN * kC);

    // 8) BN2 stats + apply + ReLU + residual -> out
    colstats<<<dim3((kB * kN) / 64), 256, 0, stream>>>(outp, stats + 2 * kC,
                                                       stats + 3 * kC, 64);
    bn_relu_add<<<dim3(2048), 256, 0, stream>>>(outp, image, out,
                                                stats + 2 * kC, stats + 3 * kC,
                                                g2, b2, 1.0f / (kB * kN),
                                                (long)kB * kN * kC / 4);
}

// Round 4
// 474.142 us; speedup vs baseline: 2.1573x; 1.1169x over previous
//
#include <hip/hip_runtime.h>
#include <hip/hip_bf16.h>
#include <math.h>

typedef __attribute__((ext_vector_type(8))) short short8;
typedef __attribute__((ext_vector_type(4))) float f32x4;

static constexpr int kB  = 16;
static constexpr int kN  = 1024;   // image tokens
static constexpr int kT  = 512;    // text tokens
static constexpr int kC  = 768;    // channels
static constexpr float kEps = 1e-5f;

__device__ inline unsigned short f2bf(float x) {        // RNE fp32 -> bf16
    unsigned u = __float_as_uint(x);
    u += 0x7FFFu + ((u >> 16) & 1u);
    return (unsigned short)(u >> 16);
}
__device__ inline float bf2f(unsigned short h) {
    return __uint_as_float(((unsigned)h) << 16);
}

// ---------------------------------------------------------------------------
// Split-bf16 MFMA GEMM:  C[M,N] = alpha * sum_seg A_seg x B_seg^T (+ bias[n])
// A: [M, 2K] bf16 rows = [hi | lo]; B: [N, 2K] bf16 rows = [hi | lo].
// FUSED segments: per BK=32 step, stage Ahi/Alo/Bhi/Blo tiles (32 KB LDS),
// then 48 MFMAs (hi*hi + lo*hi + hi*lo) between ONE barrier pair.
// Swizzle: slot = q ^ ((row>>1)&3) on both the pre-swizzled global source
// (linear LDS dest, rule #21) and the ds_read -> every 16-lane quarter-wave
// covers all 32 banks exactly 2x (2-way aliasing is free, m136).
// ---------------------------------------------------------------------------
template<bool HAS_BIAS>
__global__ __launch_bounds__(256)
void gemm_sb(const unsigned short* __restrict__ A, const unsigned short* __restrict__ B,
             float* __restrict__ C, const float* __restrict__ bias,
             int N, int Kseg, float alpha, long sA, long sB, long sC)
{
    __shared__ unsigned short Ah[128 * 32];
    __shared__ unsigned short Al[128 * 32];
    __shared__ unsigned short Bh[128 * 32];
    __shared__ unsigned short Bl[128 * 32];
    const int bz = blockIdx.z;
    A += bz * sA;  B += bz * sB;  C += bz * sC;
    const int m0 = blockIdx.y * 128, n0 = blockIdx.x * 128;
    const int tid = threadIdx.x, lane = tid & 63, wid = tid >> 6;
    const int wm = wid & 1, wn = wid >> 1;
    const long ld = 2 * (long)Kseg;

    f32x4 acc[4][4] = {};

    // ---- staging addressing (linear LDS dest, swizzled global source) ----
    // gload_lds writes 16B at (dest + lane*16); lane = srow*4 + sslot covers
    // rows r0..r0+15, slot sslot. Source k-chunk = sslot ^ swz(row), where
    // swz(row) = (row>>1)&3 (row offsets are multiples of 16 -> swz depends
    // only on srow).
    const int srow  = lane >> 2;
    const int sslot = (lane & 3) ^ ((srow >> 1) & 3);
    const int r0    = wid * 32;
    const unsigned short* gA = A + (long)(m0 + r0 + srow) * ld + sslot * 8;
    const unsigned short* gB = B + (long)(n0 + r0 + srow) * ld + sslot * 8;

    // ---- fragment-read addressing ----
    // MFMA 16x16x32 A/B operand: lane = q*16 + frow holds row frow, k-chunk q.
    // slot = q ^ swz(frow); byte addr = row*64 + slot*16.
    const int frow  = lane & 15;
    const int fslot = (lane >> 4) ^ ((frow >> 1) & 3);

    for (int k0 = 0; k0 < Kseg; k0 += 32) {
        __syncthreads();
        {
            const unsigned short* ga = gA + k0;
            const unsigned short* gb = gB + k0;
#define GLDS(dst, src) __builtin_amdgcn_global_load_lds( \
            (const __attribute__((address_space(1))) void*)(src), \
            (__attribute__((address_space(3))) void*)(dst), 16, 0, 0)
            GLDS(Ah + r0 * 32,        ga);
            GLDS(Ah + (r0 + 16) * 32, ga + 16 * ld);
            GLDS(Al + r0 * 32,        ga + Kseg);
            GLDS(Al + (r0 + 16) * 32, ga + Kseg + 16 * ld);
            GLDS(Bh + r0 * 32,        gb);
            GLDS(Bh + (r0 + 16) * 32, gb + 16 * ld);
            GLDS(Bl + r0 * 32,        gb + Kseg);
            GLDS(Bl + (r0 + 16) * 32, gb + Kseg + 16 * ld);
#undef GLDS
        }
        __syncthreads();   // drains vmcnt (global_load_lds) + orders waves

        short8 ah[4], al[4], bh[4], bl[4];
#pragma unroll
        for (int f = 0; f < 4; ++f) {
            const int ra = (wm * 64 + f * 16 + frow) * 32 + fslot * 8;
            const int rb = (wn * 64 + f * 16 + frow) * 32 + fslot * 8;
            ah[f] = *(const short8*)(Ah + ra);
            al[f] = *(const short8*)(Al + ra);
            bh[f] = *(const short8*)(Bh + rb);
            bl[f] = *(const short8*)(Bl + rb);
        }
#pragma unroll
        for (int i = 0; i < 4; ++i)
#pragma unroll
            for (int j = 0; j < 4; ++j)
                acc[i][j] = __builtin_amdgcn_mfma_f32_16x16x32_bf16(
                    ah[i], bh[j], acc[i][j], 0, 0, 0);
#pragma unroll
        for (int i = 0; i < 4; ++i)
#pragma unroll
            for (int j = 0; j < 4; ++j)
                acc[i][j] = __builtin_amdgcn_mfma_f32_16x16x32_bf16(
                    al[i], bh[j], acc[i][j], 0, 0, 0);
#pragma unroll
        for (int i = 0; i < 4; ++i)
#pragma unroll
            for (int j = 0; j < 4; ++j)
                acc[i][j] = __builtin_amdgcn_mfma_f32_16x16x32_bf16(
                    ah[i], bl[j], acc[i][j], 0, 0, 0);
    }

    // epilogue: C/D layout col=lane&15, row=(lane>>4)*4+reg
    const int cn = lane & 15, rq = lane >> 4;
#pragma unroll
    for (int j = 0; j < 4; ++j) {
        const int n = n0 + wn * 64 + j * 16 + cn;
        const float bv = HAS_BIAS ? bias[n] : 0.f;
#pragma unroll
        for (int i = 0; i < 4; ++i) {
            const int mr = m0 + wm * 64 + i * 16 + rq * 4;
#pragma unroll
            for (int r = 0; r < 4; ++r)
                C[(long)(mr + r) * N + n] = acc[i][j][r] * alpha + bv;
        }
    }
}

// ---------------------------------------------------------------------------
// Row-major split: in [R,K] fp32 -> out [R,2K] bf16 rows = [hi | lo]
// ---------------------------------------------------------------------------
__global__ void split2(const float* __restrict__ in, unsigned short* __restrict__ out,
                       int K, long total4)
{
    for (long i = blockIdx.x * (long)blockDim.x + threadIdx.x; i < total4;
         i += (long)gridDim.x * blockDim.x) {
        const long e = i * 4;
        const long row = e / K;
        const int  col = (int)(e - row * K);
        float4 x = *(const float4*)(in + e);
        ushort4 h, l;
        h.x = f2bf(x.x); l.x = f2bf(x.x - bf2f(h.x));
        h.y = f2bf(x.y); l.y = f2bf(x.y - bf2f(h.y));
        h.z = f2bf(x.z); l.z = f2bf(x.z - bf2f(h.z));
        h.w = f2bf(x.w); l.w = f2bf(x.w - bf2f(h.w));
        unsigned short* o = out + row * (long)(2 * K);
        *(ushort4*)(o + col)     = h;
        *(ushort4*)(o + K + col) = l;
    }
}

// ---------------------------------------------------------------------------
// Transpose + split (per batch): in [R,Cc] fp32 -> out [Cc, 2R] bf16
// ---------------------------------------------------------------------------
__global__ void split2_T(const float* __restrict__ in, unsigned short* __restrict__ out,
                         int R, int Cc, long sIn, long sOut)
{
    __shared__ float tile[32][33];
    const float* ib = in + (long)blockIdx.z * sIn;
    unsigned short* ob = out + (long)blockIdx.z * sOut;
    const int c0 = blockIdx.x * 32, r0 = blockIdx.y * 32;
    const int tx = threadIdx.x, ty = threadIdx.y;      // (32, 8)
#pragma unroll
    for (int it = 0; it < 4; ++it)
        tile[ty + 8 * it][tx] = ib[(long)(r0 + ty + 8 * it) * Cc + c0 + tx];
    __syncthreads();
#pragma unroll
    for (int it = 0; it < 4; ++it) {
        const int cc = ty + 8 * it;
        const float xv = tile[tx][cc];
        const unsigned short h = f2bf(xv);
        const unsigned short l = f2bf(xv - bf2f(h));
        unsigned short* o = ob + (long)(c0 + cc) * (2 * R) + r0 + tx;
        o[0] = h;  o[R] = l;
    }
}

// ---------------------------------------------------------------------------
// Per-channel sum / sumsq over rows of X [R, 768] (BN train-mode stats).
// ---------------------------------------------------------------------------
__global__ void colstats(const float* __restrict__ X, float* __restrict__ sum,
                         float* __restrict__ sumsq, int rows_per_block)
{
    const int c  = threadIdx.x;
    const long r0 = (long)blockIdx.x * rows_per_block;
    float s0 = 0, s1 = 0, s2 = 0, q0 = 0, q1 = 0, q2 = 0;
    for (int r = 0; r < rows_per_block; ++r) {
        const float* row = X + (r0 + r) * kC;
        float x0 = row[c], x1 = row[c + 256], x2 = row[c + 512];
        s0 += x0; q0 += x0 * x0;
        s1 += x1; q1 += x1 * x1;
        s2 += x2; q2 += x2 * x2;
    }
    atomicAdd(&sum[c],       s0); atomicAdd(&sumsq[c],       q0);
    atomicAdd(&sum[c + 256], s1); atomicAdd(&sumsq[c + 256], q1);
    atomicAdd(&sum[c + 512], s2); atomicAdd(&sumsq[c + 512], q2);
}

// ---------------------------------------------------------------------------
// BN1 + ReLU + split: temb fp32 [8192,768] -> temb2 bf16 [8192,1536]
// ---------------------------------------------------------------------------
__global__ void bn_relu_split2(const float* __restrict__ X, unsigned short* __restrict__ out,
                               const float* __restrict__ sum, const float* __restrict__ sumsq,
                               const float* __restrict__ g, const float* __restrict__ bta,
                               float invR, long total4)
{
    for (long i = blockIdx.x * (long)blockDim.x + threadIdx.x; i < total4;
         i += (long)gridDim.x * blockDim.x) {
        const long e = i * 4;
        const long row = e / kC;
        const int  c  = (int)(e - row * kC);
        float4 x = *(const float4*)(X + e);
        ushort4 h, l;
#pragma unroll
        for (int j = 0; j < 4; ++j) {
            const float mu  = sum[c + j] * invR;
            const float var = sumsq[c + j] * invR - mu * mu;
            float y = g[c + j] * ((&x.x)[j] - mu) * rsqrtf(var + kEps) + bta[c + j];
            y = fmaxf(y, 0.f);
            (&h.x)[j] = f2bf(y);
            (&l.x)[j] = f2bf(y - bf2f((&h.x)[j]));
        }
        unsigned short* o = out + row * (long)(2 * kC);
        *(ushort4*)(o + c)      = h;
        *(ushort4*)(o + kC + c) = l;
    }
}

// ---------------------------------------------------------------------------
// Final: out = relu(BN2(X)) + image
// ---------------------------------------------------------------------------
__global__ void bn_relu_add(const float* __restrict__ X, const float* __restrict__ img,
                            float* __restrict__ out,
                            const float* __restrict__ sum, const float* __restrict__ sumsq,
                            const float* __restrict__ g, const float* __restrict__ bta,
                            float invR, long total4)
{
    for (long i = blockIdx.x * (long)blockDim.x + threadIdx.x; i < total4;
         i += (long)gridDim.x * blockDim.x) {
        float4 x  = ((const float4*)X)[i];
        float4 im = ((const float4*)img)[i];
        const int c = (int)((i * 4) % kC);
        float4 y;
#pragma unroll
        for (int j = 0; j < 4; ++j) {
            const float mu  = sum[c + j] * invR;
            const float var = sumsq[c + j] * invR - mu * mu;
            const float yy  = g[c + j] * ((&x.x)[j] - mu) * rsqrtf(var + kEps) + bta[c + j];
            (&y.x)[j] = fmaxf(yy, 0.f) + (&im.x)[j];
        }
        ((float4*)out)[i] = y;
    }
}

// ---------------------------------------------------------------------------
// Fused per-row softmax stats + radix-256 top-k threshold + in-place masked
// softmax weights.
// ---------------------------------------------------------------------------
__global__ __launch_bounds__(256)
void topk_fused(float* __restrict__ attnT, const float* __restrict__ kfrac)
{
    __shared__ __align__(16) unsigned hist[256];
    __shared__ float redf[4];
    __shared__ unsigned sh_sel;
    __shared__ int sh_K;

    const int row  = blockIdx.x;
    const int b    = row >> 9;
    const int t    = threadIdx.x;
    const int lane = t & 63;
    const int wv   = t >> 6;
    float* x = attnT + (long)row * kN;

    float4 v = ((const float4*)x)[t];

    float m = fmaxf(fmaxf(v.x, v.y), fmaxf(v.z, v.w));
#pragma unroll
    for (int s = 32; s > 0; s >>= 1) m = fmaxf(m, __shfl_xor(m, s));
    if (lane == 0) redf[wv] = m;
    __syncthreads();
    const float M = fmaxf(fmaxf(redf[0], redf[1]), fmaxf(redf[2], redf[3]));
    __syncthreads();

    const float e0 = expf(v.x - M), e1 = expf(v.y - M);
    const float e2 = expf(v.z - M), e3 = expf(v.w - M);
    float e = (e0 + e1) + (e2 + e3);
#pragma unroll
    for (int s = 32; s > 0; s >>= 1) e += __shfl_xor(e, s);
    if (lane == 0) redf[wv] = e;
    __syncthreads();
    const float inv = 1.f / ((redf[0] + redf[1]) + (redf[2] + redf[3]));

    int K = (int)rintf((float)kN * kfrac[b]);
    float th;
    if (K <= 0) {
        th = __builtin_inff();
    } else if (K >= kN) {
        th = -__builtin_inff();
    } else {
        unsigned u[4];
#pragma unroll
        for (int j = 0; j < 4; ++j) {
            unsigned w = __float_as_uint((&v.x)[j]);
            u[j] = (w & 0x80000000u) ? ~w : (w | 0x80000000u);
        }
        unsigned prefix = 0, pm = 0;
        int Kr = K;
        for (int pos = 24; pos >= 0; pos -= 8) {
            hist[t] = 0;
            __syncthreads();
#pragma unroll
            for (int j = 0; j < 4; ++j)
                if ((u[j] & pm) == prefix)
                    atomicAdd(&hist[(u[j] >> pos) & 255u], 1u);
            __syncthreads();
            if (t < 64) {
                uint4 h = *(const uint4*)&hist[4 * t];
                unsigned s3 = h.w;
                unsigned s2 = h.z + s3;
                unsigned s1 = h.y + s2;
                unsigned s0 = h.x + s1;
                unsigned acc = s0;
#pragma unroll
                for (int s = 1; s < 64; s <<= 1) {
                    unsigned o = __shfl_down(acc, s);
                    if (lane + s < 64) acc += o;
                }
                const unsigned hiLanes = acc - s0;
                const unsigned g0 = s0 + hiLanes, g1 = s1 + hiLanes;
                const unsigned g2 = s2 + hiLanes, g3 = s3 + hiLanes;
                const unsigned kr = (unsigned)Kr;
                int dsel = -1; unsigned hex = 0;
                if      (g0 >= kr && g1 < kr)      { dsel = 4 * t + 0; hex = g1; }
                else if (g1 >= kr && g2 < kr)      { dsel = 4 * t + 1; hex = g2; }
                else if (g2 >= kr && g3 < kr)      { dsel = 4 * t + 2; hex = g3; }
                else if (g3 >= kr && hiLanes < kr) { dsel = 4 * t + 3; hex = hiLanes; }
                if (dsel >= 0) {
                    sh_sel = prefix | ((unsigned)dsel << pos);
                    sh_K   = (int)(kr - hex);
                }
            }
            __syncthreads();
            prefix = sh_sel;
            Kr     = sh_K;
            pm    |= (0xFFu << pos);
        }
        th = __uint_as_float((prefix & 0x80000000u) ? (prefix & 0x7FFFFFFFu) : ~prefix);
    }

    float4 y;
    y.x = (v.x >= th) ? e0 * inv : 0.f;
    y.y = (v.y >= th) ? e1 * inv : 0.f;
    y.z = (v.z >= th) ? e2 * inv : 0.f;
    y.w = (v.w >= th) ? e3 * inv : 0.f;
    ((float4*)x)[t] = y;
}

// ---------------------------------------------------------------------------
extern "C" void kernel_launch(void* const* d_in, const int* in_sizes, int n_in,
                              void* d_out, int out_size, void* d_ws, size_t ws_size,
                              hipStream_t stream)
{
    const float* image = (const float*)d_in[0];
    const float* text  = (const float*)d_in[1];
    const float* kfrac = (const float*)d_in[2];
    const float* Wc    = (const float*)d_in[3];
    const float* bc    = (const float*)d_in[4];
    const float* g1    = (const float*)d_in[5];
    const float* b1    = (const float*)d_in[6];
    const float* Wout  = (const float*)d_in[7];
    const float* bout  = (const float*)d_in[8];
    const float* g2    = (const float*)d_in[9];
    const float* b2    = (const float*)d_in[10];
    float* out = (float*)d_out;

    // ---- workspace arena (byte offsets, aliasing per liveness) ----
    char* ws = (char*)d_ws;
    unsigned short* Wc2    = (unsigned short*)(ws + 0);          //  2.36 MB
    unsigned short* Wout2  = (unsigned short*)(ws + 2359296);    //  2.36 MB
    float*          stats  = (float*)(ws + 4718592);             //  12 KB
    float*          v      = (float*)(ws + 4730880);             // 25.2 MB
    float*          attnT  = (float*)(ws + 29896704);            // 33.6 MB
    float*          temb   = (float*)(ws + 29896704);            // alias attnT (dead before)
    unsigned short* temb2  = (unsigned short*)(ws + 63451136);   // 25.2 MB
    unsigned short* image2 = (unsigned short*)(ws + 88616960);   // 50.3 MB
    unsigned short* text2  = (unsigned short*)(ws + 138948608);  // 25.2 MB -> end 164.1 MB
    unsigned short* attn2T = (unsigned short*)(ws + 63451136);   // alias temb2 (dead)
    unsigned short* v2T    = (unsigned short*)(ws + 97005568);   // alias image2 (dead)
    float*          outp   = (float*)(ws + 122171392);           // 50.3 MB -> end 172.5 MB

    hipMemsetAsync(stats, 0, 4 * kC * sizeof(float), stream);

    const float inv_sqrt_c = 1.0f / sqrtf((float)kC);

    // splits of raw inputs
    split2<<<dim3(1024), 256, 0, stream>>>(text,  text2,  kC, (long)kB * kT * kC / 4);
    split2<<<dim3(576),  256, 0, stream>>>(Wc,    Wc2,    kC, (long)kC * kC / 4);
    split2<<<dim3(576),  256, 0, stream>>>(Wout,  Wout2,  kC, (long)kC * kC / 4);
    split2<<<dim3(2048), 256, 0, stream>>>(image, image2, kC, (long)kB * kN * kC / 4);

    // 1) temb = text @ Wc^T + bc
    gemm_sb<true><<<dim3(kC / 128, (kB * kT) / 128, 1), 256, 0, stream>>>(
        text2, Wc2, temb, bc, kC, kC, 1.0f, 0, 0, 0);

    // 2) BN1 stats + apply + ReLU + split -> temb2
    colstats<<<dim3((kB * kT) / 64), 256, 0, stream>>>(temb, stats, stats + kC, 64);
    bn_relu_split2<<<dim3(1024), 256, 0, stream>>>(temb, temb2, stats, stats + kC,
                                                   g1, b1, 1.0f / (kB * kT),
                                                   (long)kB * kT * kC / 4);

    // 3) v = text @ Wout^T + bout
    gemm_sb<true><<<dim3(kC / 128, (kB * kT) / 128, 1), 256, 0, stream>>>(
        text2, Wout2, v, bout, kC, kC, 1.0f, 0, 0, 0);

    // 4) attnT[b] = temb[b] @ image[b]^T / sqrt(C)
    gemm_sb<false><<<dim3(kN / 128, kT / 128, kB), 256, 0, stream>>>(
        temb2, image2, attnT, nullptr, kN, kC, inv_sqrt_c,
        (long)kT * 2 * kC, (long)kN * 2 * kC, (long)kT * kN);

    // 5) fused softmax stats + top-k threshold + masked weights (in place)
    topk_fused<<<dim3(kB * kT), 256, 0, stream>>>(attnT, kfrac);

    // 6) transpose+split masked weights and v for the TN product
    split2_T<<<dim3(kN / 32, kT / 32, kB), dim3(32, 8), 0, stream>>>(
        attnT, attn2T, kT, kN, (long)kT * kN, (long)kN * 2 * kT);
    split2_T<<<dim3(kC / 32, kT / 32, kB), dim3(32, 8), 0, stream>>>(
        v, v2T, kT, kC, (long)kT * kC, (long)kC * 2 * kT);

    // 7) outp[b] = W[b] @ v[b]   (M=1024, N=768, Kseg=512)
    gemm_sb<false><<<dim3(kC / 128, kN / 128, kB), 256, 0, stream>>>(
        attn2T, v2T, outp, nullptr, kC, kT, 1.0f,
        (long)kN * 2 * kT, (long)kC * 2 * kT, (long)kN * kC);

    // 8) BN2 stats + apply + ReLU + residual -> out
    colstats<<<dim3((kB * kN) / 64), 256, 0, stream>>>(outp, stats + 2 * kC,
                                                       stats + 3 * kC, 64);
    bn_relu_add<<<dim3(2048), 256, 0, stream>>>(outp, image, out,
                                                stats + 2 * kC, stats + 3 * kC,
                                                g2, b2, 1.0f / (kB * kN),
                                                (long)kB * kN * kC / 4);
}

// Round 5
// 422.428 us; speedup vs baseline: 2.4214x; 1.1224x over previous
//
#include <hip/hip_runtime.h>
#include <hip/hip_bf16.h>
#include <math.h>

typedef __attribute__((ext_vector_type(8))) short short8;
typedef __attribute__((ext_vector_type(4))) float f32x4;

static constexpr int kB  = 16;
static constexpr int kN  = 1024;   // image tokens
static constexpr int kT  = 512;    // text tokens
static constexpr int kC  = 768;    // channels
static constexpr float kEps = 1e-5f;

__device__ inline unsigned short f2bf(float x) {        // RNE fp32 -> bf16
    unsigned u = __float_as_uint(x);
    u += 0x7FFFu + ((u >> 16) & 1u);
    return (unsigned short)(u >> 16);
}
__device__ inline float bf2f(unsigned short h) {
    return __uint_as_float(((unsigned)h) << 16);
}

// ---------------------------------------------------------------------------
// Split-bf16 MFMA GEMM:  C[M,N] = alpha * sum_seg A_seg x B_seg^T (+ bias[n])
// A: [M, 2K] bf16 rows = [hi | lo]; B: [N, 2K] bf16 rows = [hi | lo].
// Fused segments: per BK=32 step stage Ahi/Alo/Bhi/Blo (32 KB), 48 MFMAs.
// NEW vs r4 (counters showed HBM-bound over-fetch + exposed latency):
//  - double-buffered LDS (64 KB) + counted `s_waitcnt vmcnt(8)` before a raw
//    s_barrier: next k-step's 8 gload_lds stay in flight across the barrier
//    (T4); only the last iteration drains to vmcnt(0).
//  - XCD-chunked bijective 1D-grid remap (T1): panel-sharing blocks land on
//    the same XCD L2 -> cut the 2.2x HBM over-fetch.
// Swizzle (unchanged, verified 0 conflicts): slot = q ^ ((row>>1)&3) on both
// the pre-swizzled global source (linear LDS dest) and the ds_read.
// ---------------------------------------------------------------------------
template<bool HAS_BIAS>
__global__ __launch_bounds__(256)
void gemm_sb(const unsigned short* __restrict__ A, const unsigned short* __restrict__ B,
             float* __restrict__ C, const float* __restrict__ bias,
             int N, int Kseg, float alpha, long sA, long sB, long sC,
             int gx, int gy)
{
    __shared__ unsigned short Ah[2][128 * 32];
    __shared__ unsigned short Al[2][128 * 32];
    __shared__ unsigned short Bh[2][128 * 32];
    __shared__ unsigned short Bl[2][128 * 32];

    // XCD-chunked bijective remap (all grids divisible by 8)
    const unsigned nwg = gridDim.x;
    unsigned g = (blockIdx.x & 7u) * (nwg >> 3) + (blockIdx.x >> 3);
    const int bxx = (int)(g % (unsigned)gx);  g /= (unsigned)gx;
    const int byy = (int)(g % (unsigned)gy);
    const int bz  = (int)(g / (unsigned)gy);

    A += (long)bz * sA;  B += (long)bz * sB;  C += (long)bz * sC;
    const int m0 = byy * 128, n0 = bxx * 128;
    const int tid = threadIdx.x, lane = tid & 63, wid = tid >> 6;
    const int wm = wid & 1, wn = wid >> 1;
    const long ld = 2 * (long)Kseg;

    f32x4 acc[4][4] = {};

    // staging: lane = srow*4 + slot covers 16 rows x 4 slots; linear LDS dest,
    // swizzled global source chunk = slot ^ ((row>>1)&3)
    const int srow  = lane >> 2;
    const int sslot = (lane & 3) ^ ((srow >> 1) & 3);
    const int r0    = wid * 32;
    const unsigned short* gA = A + (long)(m0 + r0 + srow) * ld + sslot * 8;
    const unsigned short* gB = B + (long)(n0 + r0 + srow) * ld + sslot * 8;

    // fragment reads: lane = q*16 + frow; slot = q ^ ((frow>>1)&3)
    const int frow  = lane & 15;
    const int fslot = (lane >> 4) ^ ((frow >> 1) & 3);

    const int NK = Kseg / 32;

#define GLDS(dst, src) __builtin_amdgcn_global_load_lds( \
        (const __attribute__((address_space(1))) void*)(src), \
        (__attribute__((address_space(3))) void*)(dst), 16, 0, 0)
    auto stage = [&](int ks, int p) {
        const unsigned short* ga = gA + ks * 32;
        const unsigned short* gb = gB + ks * 32;
        GLDS(&Ah[p][r0 * 32],        ga);
        GLDS(&Ah[p][(r0 + 16) * 32], ga + 16 * ld);
        GLDS(&Al[p][r0 * 32],        ga + Kseg);
        GLDS(&Al[p][(r0 + 16) * 32], ga + Kseg + 16 * ld);
        GLDS(&Bh[p][r0 * 32],        gb);
        GLDS(&Bh[p][(r0 + 16) * 32], gb + 16 * ld);
        GLDS(&Bl[p][r0 * 32],        gb + Kseg);
        GLDS(&Bl[p][(r0 + 16) * 32], gb + Kseg + 16 * ld);
    };
#undef GLDS

    stage(0, 0);                               // prologue
    for (int ks = 0; ks < NK; ++ks) {
        const int p = ks & 1;
        if (ks + 1 < NK) {
            stage(ks + 1, p ^ 1);              // 8 loads in flight across barrier
            asm volatile("s_waitcnt vmcnt(8)" ::: "memory");   // my buf[p] landed
        } else {
            asm volatile("s_waitcnt vmcnt(0)" ::: "memory");
        }
        __builtin_amdgcn_s_barrier();          // all waves' buf[p] in LDS

        short8 ah[4], al[4], bh[4], bl[4];
#pragma unroll
        for (int f = 0; f < 4; ++f) {
            const int ra = (wm * 64 + f * 16 + frow) * 32 + fslot * 8;
            const int rb = (wn * 64 + f * 16 + frow) * 32 + fslot * 8;
            ah[f] = *(const short8*)(&Ah[p][ra]);
            al[f] = *(const short8*)(&Al[p][ra]);
            bh[f] = *(const short8*)(&Bh[p][rb]);
            bl[f] = *(const short8*)(&Bl[p][rb]);
        }
#pragma unroll
        for (int i = 0; i < 4; ++i)
#pragma unroll
            for (int j = 0; j < 4; ++j)
                acc[i][j] = __builtin_amdgcn_mfma_f32_16x16x32_bf16(
                    ah[i], bh[j], acc[i][j], 0, 0, 0);
#pragma unroll
        for (int i = 0; i < 4; ++i)
#pragma unroll
            for (int j = 0; j < 4; ++j)
                acc[i][j] = __builtin_amdgcn_mfma_f32_16x16x32_bf16(
                    al[i], bh[j], acc[i][j], 0, 0, 0);
#pragma unroll
        for (int i = 0; i < 4; ++i)
#pragma unroll
            for (int j = 0; j < 4; ++j)
                acc[i][j] = __builtin_amdgcn_mfma_f32_16x16x32_bf16(
                    ah[i], bl[j], acc[i][j], 0, 0, 0);

        __builtin_amdgcn_s_barrier();          // reads of buf[p] done
    }

    // epilogue: C/D layout col=lane&15, row=(lane>>4)*4+reg
    const int cn = lane & 15, rq = lane >> 4;
#pragma unroll
    for (int j = 0; j < 4; ++j) {
        const int n = n0 + wn * 64 + j * 16 + cn;
        const float bv = HAS_BIAS ? bias[n] : 0.f;
#pragma unroll
        for (int i = 0; i < 4; ++i) {
            const int mr = m0 + wm * 64 + i * 16 + rq * 4;
#pragma unroll
            for (int r = 0; r < 4; ++r)
                C[(long)(mr + r) * N + n] = acc[i][j][r] * alpha + bv;
        }
    }
}

// ---------------------------------------------------------------------------
// Row-major split: in [R,K] fp32 -> out [R,2K] bf16 rows = [hi | lo]
// ---------------------------------------------------------------------------
__global__ void split2(const float* __restrict__ in, unsigned short* __restrict__ out,
                       int K, long total4)
{
    for (long i = blockIdx.x * (long)blockDim.x + threadIdx.x; i < total4;
         i += (long)gridDim.x * blockDim.x) {
        const long e = i * 4;
        const long row = e / K;
        const int  col = (int)(e - row * K);
        float4 x = *(const float4*)(in + e);
        ushort4 h, l;
        h.x = f2bf(x.x); l.x = f2bf(x.x - bf2f(h.x));
        h.y = f2bf(x.y); l.y = f2bf(x.y - bf2f(h.y));
        h.z = f2bf(x.z); l.z = f2bf(x.z - bf2f(h.z));
        h.w = f2bf(x.w); l.w = f2bf(x.w - bf2f(h.w));
        unsigned short* o = out + row * (long)(2 * K);
        *(ushort4*)(o + col)     = h;
        *(ushort4*)(o + K + col) = l;
    }
}

// ---------------------------------------------------------------------------
// Transpose + split (per batch): in [R,Cc] fp32 -> out [Cc, 2R] bf16
// ---------------------------------------------------------------------------
__global__ void split2_T(const float* __restrict__ in, unsigned short* __restrict__ out,
                         int R, int Cc, long sIn, long sOut)
{
    __shared__ float tile[32][33];
    const float* ib = in + (long)blockIdx.z * sIn;
    unsigned short* ob = out + (long)blockIdx.z * sOut;
    const int c0 = blockIdx.x * 32, r0 = blockIdx.y * 32;
    const int tx = threadIdx.x, ty = threadIdx.y;      // (32, 8)
#pragma unroll
    for (int it = 0; it < 4; ++it)
        tile[ty + 8 * it][tx] = ib[(long)(r0 + ty + 8 * it) * Cc + c0 + tx];
    __syncthreads();
#pragma unroll
    for (int it = 0; it < 4; ++it) {
        const int cc = ty + 8 * it;
        const float xv = tile[tx][cc];
        const unsigned short h = f2bf(xv);
        const unsigned short l = f2bf(xv - bf2f(h));
        unsigned short* o = ob + (long)(c0 + cc) * (2 * R) + r0 + tx;
        o[0] = h;  o[R] = l;
    }
}

// ---------------------------------------------------------------------------
// Per-channel sum / sumsq over rows of X [R, 768] (BN train-mode stats).
// ---------------------------------------------------------------------------
__global__ void colstats(const float* __restrict__ X, float* __restrict__ sum,
                         float* __restrict__ sumsq, int rows_per_block)
{
    const int c  = threadIdx.x;
    const long r0 = (long)blockIdx.x * rows_per_block;
    float s0 = 0, s1 = 0, s2 = 0, q0 = 0, q1 = 0, q2 = 0;
    for (int r = 0; r < rows_per_block; ++r) {
        const float* row = X + (r0 + r) * kC;
        float x0 = row[c], x1 = row[c + 256], x2 = row[c + 512];
        s0 += x0; q0 += x0 * x0;
        s1 += x1; q1 += x1 * x1;
        s2 += x2; q2 += x2 * x2;
    }
    atomicAdd(&sum[c],       s0); atomicAdd(&sumsq[c],       q0);
    atomicAdd(&sum[c + 256], s1); atomicAdd(&sumsq[c + 256], q1);
    atomicAdd(&sum[c + 512], s2); atomicAdd(&sumsq[c + 512], q2);
}

// ---------------------------------------------------------------------------
// BN1 + ReLU + split: temb fp32 [8192,768] -> temb2 bf16 [8192,1536]
// ---------------------------------------------------------------------------
__global__ void bn_relu_split2(const float* __restrict__ X, unsigned short* __restrict__ out,
                               const float* __restrict__ sum, const float* __restrict__ sumsq,
                               const float* __restrict__ g, const float* __restrict__ bta,
                               float invR, long total4)
{
    for (long i = blockIdx.x * (long)blockDim.x + threadIdx.x; i < total4;
         i += (long)gridDim.x * blockDim.x) {
        const long e = i * 4;
        const long row = e / kC;
        const int  c  = (int)(e - row * kC);
        float4 x = *(const float4*)(X + e);
        ushort4 h, l;
#pragma unroll
        for (int j = 0; j < 4; ++j) {
            const float mu  = sum[c + j] * invR;
            const float var = sumsq[c + j] * invR - mu * mu;
            float y = g[c + j] * ((&x.x)[j] - mu) * rsqrtf(var + kEps) + bta[c + j];
            y = fmaxf(y, 0.f);
            (&h.x)[j] = f2bf(y);
            (&l.x)[j] = f2bf(y - bf2f((&h.x)[j]));
        }
        unsigned short* o = out + row * (long)(2 * kC);
        *(ushort4*)(o + c)      = h;
        *(ushort4*)(o + kC + c) = l;
    }
}

// ---------------------------------------------------------------------------
// Final: out = relu(BN2(X)) + image
// ---------------------------------------------------------------------------
__global__ void bn_relu_add(const float* __restrict__ X, const float* __restrict__ img,
                            float* __restrict__ out,
                            const float* __restrict__ sum, const float* __restrict__ sumsq,
                            const float* __restrict__ g, const float* __restrict__ bta,
                            float invR, long total4)
{
    for (long i = blockIdx.x * (long)blockDim.x + threadIdx.x; i < total4;
         i += (long)gridDim.x * blockDim.x) {
        float4 x  = ((const float4*)X)[i];
        float4 im = ((const float4*)img)[i];
        const int c = (int)((i * 4) % kC);
        float4 y;
#pragma unroll
        for (int j = 0; j < 4; ++j) {
            const float mu  = sum[c + j] * invR;
            const float var = sumsq[c + j] * invR - mu * mu;
            const float yy  = g[c + j] * ((&x.x)[j] - mu) * rsqrtf(var + kEps) + bta[c + j];
            (&y.x)[j] = fmaxf(yy, 0.f) + (&im.x)[j];
        }
        ((float4*)out)[i] = y;
    }
}

// ---------------------------------------------------------------------------
// Fused per-row softmax stats + radix-256 top-k threshold + in-place masked
// softmax weights.
// ---------------------------------------------------------------------------
__global__ __launch_bounds__(256)
void topk_fused(float* __restrict__ attnT, const float* __restrict__ kfrac)
{
    __shared__ __align__(16) unsigned hist[256];
    __shared__ float redf[4];
    __shared__ unsigned sh_sel;
    __shared__ int sh_K;

    const int row  = blockIdx.x;
    const int b    = row >> 9;
    const int t    = threadIdx.x;
    const int lane = t & 63;
    const int wv   = t >> 6;
    float* x = attnT + (long)row * kN;

    float4 v = ((const float4*)x)[t];

    float m = fmaxf(fmaxf(v.x, v.y), fmaxf(v.z, v.w));
#pragma unroll
    for (int s = 32; s > 0; s >>= 1) m = fmaxf(m, __shfl_xor(m, s));
    if (lane == 0) redf[wv] = m;
    __syncthreads();
    const float M = fmaxf(fmaxf(redf[0], redf[1]), fmaxf(redf[2], redf[3]));
    __syncthreads();

    const float e0 = expf(v.x - M), e1 = expf(v.y - M);
    const float e2 = expf(v.z - M), e3 = expf(v.w - M);
    float e = (e0 + e1) + (e2 + e3);
#pragma unroll
    for (int s = 32; s > 0; s >>= 1) e += __shfl_xor(e, s);
    if (lane == 0) redf[wv] = e;
    __syncthreads();
    const float inv = 1.f / ((redf[0] + redf[1]) + (redf[2] + redf[3]));

    int K = (int)rintf((float)kN * kfrac[b]);
    float th;
    if (K <= 0) {
        th = __builtin_inff();
    } else if (K >= kN) {
        th = -__builtin_inff();
    } else {
        unsigned u[4];
#pragma unroll
        for (int j = 0; j < 4; ++j) {
            unsigned w = __float_as_uint((&v.x)[j]);
            u[j] = (w & 0x80000000u) ? ~w : (w | 0x80000000u);
        }
        unsigned prefix = 0, pm = 0;
        int Kr = K;
        for (int pos = 24; pos >= 0; pos -= 8) {
            hist[t] = 0;
            __syncthreads();
#pragma unroll
            for (int j = 0; j < 4; ++j)
                if ((u[j] & pm) == prefix)
                    atomicAdd(&hist[(u[j] >> pos) & 255u], 1u);
            __syncthreads();
            if (t < 64) {
                uint4 h = *(const uint4*)&hist[4 * t];
                unsigned s3 = h.w;
                unsigned s2 = h.z + s3;
                unsigned s1 = h.y + s2;
                unsigned s0 = h.x + s1;
                unsigned acc = s0;
#pragma unroll
                for (int s = 1; s < 64; s <<= 1) {
                    unsigned o = __shfl_down(acc, s);
                    if (lane + s < 64) acc += o;
                }
                const unsigned hiLanes = acc - s0;
                const unsigned g0 = s0 + hiLanes, g1 = s1 + hiLanes;
                const unsigned g2 = s2 + hiLanes, g3 = s3 + hiLanes;
                const unsigned kr = (unsigned)Kr;
                int dsel = -1; unsigned hex = 0;
                if      (g0 >= kr && g1 < kr)      { dsel = 4 * t + 0; hex = g1; }
                else if (g1 >= kr && g2 < kr)      { dsel = 4 * t + 1; hex = g2; }
                else if (g2 >= kr && g3 < kr)      { dsel = 4 * t + 2; hex = g3; }
                else if (g3 >= kr && hiLanes < kr) { dsel = 4 * t + 3; hex = hiLanes; }
                if (dsel >= 0) {
                    sh_sel = prefix | ((unsigned)dsel << pos);
                    sh_K   = (int)(kr - hex);
                }
            }
            __syncthreads();
            prefix = sh_sel;
            Kr     = sh_K;
            pm    |= (0xFFu << pos);
        }
        th = __uint_as_float((prefix & 0x80000000u) ? (prefix & 0x7FFFFFFFu) : ~prefix);
    }

    float4 y;
    y.x = (v.x >= th) ? e0 * inv : 0.f;
    y.y = (v.y >= th) ? e1 * inv : 0.f;
    y.z = (v.z >= th) ? e2 * inv : 0.f;
    y.w = (v.w >= th) ? e3 * inv : 0.f;
    ((float4*)x)[t] = y;
}

// ---------------------------------------------------------------------------
extern "C" void kernel_launch(void* const* d_in, const int* in_sizes, int n_in,
                              void* d_out, int out_size, void* d_ws, size_t ws_size,
                              hipStream_t stream)
{
    const float* image = (const float*)d_in[0];
    const float* text  = (const float*)d_in[1];
    const float* kfrac = (const float*)d_in[2];
    const float* Wc    = (const float*)d_in[3];
    const float* bc    = (const float*)d_in[4];
    const float* g1    = (const float*)d_in[5];
    const float* b1    = (const float*)d_in[6];
    const float* Wout  = (const float*)d_in[7];
    const float* bout  = (const float*)d_in[8];
    const float* g2    = (const float*)d_in[9];
    const float* b2    = (const float*)d_in[10];
    float* out = (float*)d_out;

    // ---- workspace arena (byte offsets, aliasing per liveness) ----
    char* ws = (char*)d_ws;
    unsigned short* Wc2    = (unsigned short*)(ws + 0);          //  2.36 MB
    unsigned short* Wout2  = (unsigned short*)(ws + 2359296);    //  2.36 MB
    float*          stats  = (float*)(ws + 4718592);             //  12 KB
    float*          v      = (float*)(ws + 4730880);             // 25.2 MB
    float*          attnT  = (float*)(ws + 29896704);            // 33.6 MB
    float*          temb   = (float*)(ws + 29896704);            // alias attnT (dead before)
    unsigned short* temb2  = (unsigned short*)(ws + 63451136);   // 25.2 MB
    unsigned short* image2 = (unsigned short*)(ws + 88616960);   // 50.3 MB
    unsigned short* text2  = (unsigned short*)(ws + 138948608);  // 25.2 MB -> end 164.1 MB
    unsigned short* attn2T = (unsigned short*)(ws + 63451136);   // alias temb2 (dead)
    unsigned short* v2T    = (unsigned short*)(ws + 97005568);   // alias image2 (dead)
    float*          outp   = (float*)(ws + 122171392);           // 50.3 MB -> end 172.5 MB

    hipMemsetAsync(stats, 0, 4 * kC * sizeof(float), stream);

    const float inv_sqrt_c = 1.0f / sqrtf((float)kC);

    // splits of raw inputs
    split2<<<dim3(1024), 256, 0, stream>>>(text,  text2,  kC, (long)kB * kT * kC / 4);
    split2<<<dim3(576),  256, 0, stream>>>(Wc,    Wc2,    kC, (long)kC * kC / 4);
    split2<<<dim3(576),  256, 0, stream>>>(Wout,  Wout2,  kC, (long)kC * kC / 4);
    split2<<<dim3(2048), 256, 0, stream>>>(image, image2, kC, (long)kB * kN * kC / 4);

    // 1) temb = text @ Wc^T + bc          grid 6x64 -> 384
    gemm_sb<true><<<384, 256, 0, stream>>>(
        text2, Wc2, temb, bc, kC, kC, 1.0f, 0, 0, 0, 6, 64);

    // 2) BN1 stats + apply + ReLU + split -> temb2
    colstats<<<dim3((kB * kT) / 64), 256, 0, stream>>>(temb, stats, stats + kC, 64);
    bn_relu_split2<<<dim3(1024), 256, 0, stream>>>(temb, temb2, stats, stats + kC,
                                                   g1, b1, 1.0f / (kB * kT),
                                                   (long)kB * kT * kC / 4);

    // 3) v = text @ Wout^T + bout         grid 6x64 -> 384
    gemm_sb<true><<<384, 256, 0, stream>>>(
        text2, Wout2, v, bout, kC, kC, 1.0f, 0, 0, 0, 6, 64);

    // 4) attnT[b] = temb[b] @ image[b]^T / sqrt(C)   grid 8x4x16 -> 512
    gemm_sb<false><<<512, 256, 0, stream>>>(
        temb2, image2, attnT, nullptr, kN, kC, inv_sqrt_c,
        (long)kT * 2 * kC, (long)kN * 2 * kC, (long)kT * kN, 8, 4);

    // 5) fused softmax stats + top-k threshold + masked weights (in place)
    topk_fused<<<dim3(kB * kT), 256, 0, stream>>>(attnT, kfrac);

    // 6) transpose+split masked weights and v for the TN product
    split2_T<<<dim3(kN / 32, kT / 32, kB), dim3(32, 8), 0, stream>>>(
        attnT, attn2T, kT, kN, (long)kT * kN, (long)kN * 2 * kT);
    split2_T<<<dim3(kC / 32, kT / 32, kB), dim3(32, 8), 0, stream>>>(
        v, v2T, kT, kC, (long)kT * kC, (long)kC * 2 * kT);

    // 7) outp[b] = W[b] @ v[b]   grid 6x8x16 -> 768, Kseg=512
    gemm_sb<false><<<768, 256, 0, stream>>>(
        attn2T, v2T, outp, nullptr, kC, kT, 1.0f,
        (long)kN * 2 * kT, (long)kC * 2 * kT, (long)kN * kC, 6, 8);

    // 8) BN2 stats + apply + ReLU + residual -> out
    colstats<<<dim3((kB * kN) / 64), 256, 0, stream>>>(outp, stats + 2 * kC,
                                                       stats + 3 * kC, 64);
    bn_relu_add<<<dim3(2048), 256, 0, stream>>>(outp, image, out,
                                                stats + 2 * kC, stats + 3 * kC,
                                                g2, b2, 1.0f / (kB * kN),
                                                (long)kB * kN * kC / 4);
}